// Round 1
// baseline (1616.609 us; speedup 1.0000x reference)
//
#include <hip/hip_runtime.h>
#include <math.h>

// Problem constants
#define NH    8
#define KD    64
#define BLK   8
#define HALO_ 4
#define KVK   16     // KV_KERNEL = BLOCK + 2*HALO
#define EMB_  512
#define B_    8
#define HW_   64
#define C_    512
#define HB_   8      // H / BLOCK
#define M_TOT (B_*HW_*HW_)   // 32768 pixels

// ---------------------------------------------------------------------------
// Kernel 1: fused projection GEMM.  x (32768 x 512) @ [wq | wkv] (512 x 1536)
// Writes q (scaled), k, v as (pixel, n*64+d) fp32 arrays.
// BM=128, BN=64, BK=16, 256 threads, 8x4 per thread.
// ---------------------------------------------------------------------------
__global__ __launch_bounds__(256) void proj_gemm(
    const float* __restrict__ x, const float* __restrict__ wq,
    const float* __restrict__ wkv,
    float* __restrict__ qbuf, float* __restrict__ kbuf, float* __restrict__ vbuf)
{
    __shared__ float As[16][132];   // transposed A tile [k][m], padded
    __shared__ float Bs[16][68];    // [k][n], padded

    const int bm = blockIdx.x;      // 256 row tiles
    const int bn = blockIdx.y;      // 24 col tiles
    const int t  = threadIdx.x;
    const int tx = t & 15, ty = t >> 4;

    const int n0g = bn * 64;
    const float* wsrc; int ldw, ncol;
    if (n0g < 512) { wsrc = wq;  ldw = 512;  ncol = n0g; }
    else           { wsrc = wkv; ldw = 1024; ncol = n0g - 512; }

    const int ar = t >> 2;          // A load: row within 64-row half
    const int ac = (t & 3) * 4;     // A load: k-col (float4)
    const int bk = t >> 4;          // B load: k row
    const int bc = (t & 15) * 4;    // B load: n col (float4)

    float acc[8][4] = {};

    for (int k0 = 0; k0 < 512; k0 += 16) {
        #pragma unroll
        for (int it = 0; it < 2; ++it) {
            int r = ar + it * 64;
            const float4 av = *(const float4*)&x[(size_t)(bm*128 + r)*512 + k0 + ac];
            As[ac+0][r] = av.x; As[ac+1][r] = av.y;
            As[ac+2][r] = av.z; As[ac+3][r] = av.w;
        }
        *(float4*)&Bs[bk][bc] = *(const float4*)&wsrc[(size_t)(k0 + bk)*ldw + ncol + bc];
        __syncthreads();

        #pragma unroll
        for (int kk = 0; kk < 16; ++kk) {
            float a[8], bv[4];
            *(float4*)&a[0] = *(const float4*)&As[kk][ty*8];
            *(float4*)&a[4] = *(const float4*)&As[kk][ty*8+4];
            *(float4*)&bv[0] = *(const float4*)&Bs[kk][tx*4];
            #pragma unroll
            for (int i = 0; i < 8; ++i)
                #pragma unroll
                for (int j = 0; j < 4; ++j)
                    acc[i][j] = fmaf(a[i], bv[j], acc[i][j]);
        }
        __syncthreads();
    }

    const float scale = 0.125f;     // KEY_DIM^-0.5
    const int m0 = bm*128 + ty*8;
    const int n  = n0g + tx*4;
    if (n0g < 512) {
        #pragma unroll
        for (int i = 0; i < 8; ++i) {
            float4 v = { acc[i][0]*scale, acc[i][1]*scale, acc[i][2]*scale, acc[i][3]*scale };
            *(float4*)&qbuf[(size_t)(m0+i)*512 + n] = v;
        }
    } else {
        const int jj = n - 512;
        const int head = jj >> 7;       // which head (128 ch per head in kv)
        const int dd = jj & 127;        // 0..63 key, 64..127 value
        float* dst = (dd < 64) ? kbuf : vbuf;
        const int d2 = dd & 63;
        #pragma unroll
        for (int i = 0; i < 8; ++i) {
            float4 v = { acc[i][0], acc[i][1], acc[i][2], acc[i][3] };
            *(float4*)&dst[(size_t)(m0+i)*512 + head*64 + d2] = v;
        }
    }
}

// ---------------------------------------------------------------------------
// Kernel 2: halo attention.  One workgroup per (b, head, hb, wb) = 4096 blocks.
// 256 threads: thread = (q = t&63, g = t>>6 wave id).
// Phase layout: stage pos tables + K tile + q regs -> pos logits -> scores
// (+pos bias) -> softmax -> reload V over K -> PV -> write.
// Writes attn output (aliases q buffer; safe, see kernel_launch).
// ---------------------------------------------------------------------------
__global__ __launch_bounds__(256, 1) void halo_attn(
    const float* __restrict__ qbuf, const float* __restrict__ kbuf,
    const float* __restrict__ vbuf,
    const float* __restrict__ posw, const float* __restrict__ posh,
    float* __restrict__ obuf)
{
    __shared__ float kv[256][64];    // 64 KB: K tile, then V tile
    __shared__ float sp[64][257];    // 65.8 KB: softmax numerators (padded)
    __shared__ float pw[64][32];     // pos_w staged [d][idx]
    __shared__ float ph[64][32];     // pos_h staged [d][idx]
    __shared__ float posq[64][33];   // [q][c]: c<16 -> rel_w(kj), c>=16 -> rel_h(ki)
    __shared__ float red[4][64];     // per-wave max
    __shared__ float red2[4][64];    // per-wave sum

    const int wg = blockIdx.x;
    const int wb = wg & 7, hb = (wg >> 3) & 7, n = (wg >> 6) & 7, b = wg >> 9;
    const int t = threadIdx.x;
    const int q = t & 63, g = t >> 6;
    const int qi = q >> 3, qj = q & 7;

    // stage pos tables (64 x 31 each)
    for (int j = t; j < 64*31; j += 256) {
        int d = j / 31, idx = j % 31;
        pw[d][idx] = posw[j];
        ph[d][idx] = posh[j];
    }

    // load K tile (256 spatial x 64 dim), zero outside image
    const int sc = (t & 15) * 4;
    for (int it = 0; it < 16; ++it) {
        int s = it*16 + (t >> 4);
        int ki = s >> 4, kj = s & 15;
        int y = hb*8 - 4 + ki, x = wb*8 - 4 + kj;
        float4 v = make_float4(0.f, 0.f, 0.f, 0.f);
        if ((unsigned)y < 64u && (unsigned)x < 64u)
            v = *(const float4*)&kbuf[((size_t)((b*64 + y)*64 + x))*512 + n*64 + sc];
        *(float4*)&kv[s][sc] = v;
    }

    // load this thread's q row (already scaled) into registers
    float qr[64];
    {
        int y = hb*8 + qi, x = wb*8 + qj;
        const float* src = &qbuf[((size_t)((b*64 + y)*64 + x))*512 + n*64];
        #pragma unroll
        for (int d4 = 0; d4 < 16; ++d4)
            *(float4*)&qr[d4*4] = *(const float4*)&src[d4*4];
    }
    __syncthreads();

    // relative position logits: posq[q][c], c<16: kj-axis, c>=16: ki-axis
    #pragma unroll
    for (int j = 0; j < 8; ++j) {
        int c = g*8 + j;
        int idx = (c < 16) ? (c - qj + 15) : ((c - 16) - qi + 15);  // in [8,30]
        float (*tab)[32] = (c < 16) ? pw : ph;
        float acc = 0.f;
        #pragma unroll
        for (int d = 0; d < 64; ++d)
            acc = fmaf(qr[d], tab[d][idx], acc);
        posq[q][c] = acc;
    }
    __syncthreads();

    // scores for this wave's 64 keys
    float sreg[64];
    float mloc = -1e30f;
    #pragma unroll
    for (int i = 0; i < 64; ++i) {
        int kk = g*64 + i;
        int ki = kk >> 4, kj = kk & 15;
        float acc = 0.f;
        #pragma unroll
        for (int d4 = 0; d4 < 16; ++d4) {
            float4 kx = *(const float4*)&kv[kk][d4*4];
            acc = fmaf(qr[d4*4+0], kx.x, acc);
            acc = fmaf(qr[d4*4+1], kx.y, acc);
            acc = fmaf(qr[d4*4+2], kx.z, acc);
            acc = fmaf(qr[d4*4+3], kx.w, acc);
        }
        acc += posq[q][kj] + posq[q][16 + ki];
        sreg[i] = acc;
        mloc = fmaxf(mloc, acc);
    }
    red[g][q] = mloc;
    __syncthreads();

    const float m = fmaxf(fmaxf(red[0][q], red[1][q]), fmaxf(red[2][q], red[3][q]));
    float ssum = 0.f;
    #pragma unroll
    for (int i = 0; i < 64; ++i) {
        float p = __expf(sreg[i] - m);
        sp[q][g*64 + i] = p;
        ssum += p;
    }
    red2[g][q] = ssum;
    __syncthreads();    // all K reads + sp/red2 writes done

    // load V tile over kv
    for (int it = 0; it < 16; ++it) {
        int s = it*16 + (t >> 4);
        int ki = s >> 4, kj = s & 15;
        int y = hb*8 - 4 + ki, x = wb*8 - 4 + kj;
        float4 v = make_float4(0.f, 0.f, 0.f, 0.f);
        if ((unsigned)y < 64u && (unsigned)x < 64u)
            v = *(const float4*)&vbuf[((size_t)((b*64 + y)*64 + x))*512 + n*64 + sc];
        *(float4*)&kv[s][sc] = v;
    }
    __syncthreads();

    // PV: thread (q, g) owns output dims [g*16, g*16+16)
    const float denom = red2[0][q] + red2[1][q] + red2[2][q] + red2[3][q];
    const float inv = 1.f / denom;
    float o[16] = {};
    for (int kk = 0; kk < 256; ++kk) {
        float p = sp[q][kk];
        #pragma unroll
        for (int j4 = 0; j4 < 4; ++j4) {
            float4 vv = *(const float4*)&kv[kk][g*16 + j4*4];
            o[j4*4+0] = fmaf(p, vv.x, o[j4*4+0]);
            o[j4*4+1] = fmaf(p, vv.y, o[j4*4+1]);
            o[j4*4+2] = fmaf(p, vv.z, o[j4*4+2]);
            o[j4*4+3] = fmaf(p, vv.w, o[j4*4+3]);
        }
    }
    {
        int y = hb*8 + qi, x = wb*8 + qj;
        float* dst = &obuf[((size_t)((b*64 + y)*64 + x))*512 + n*64 + g*16];
        #pragma unroll
        for (int j4 = 0; j4 < 4; ++j4) {
            float4 vv = { o[j4*4+0]*inv, o[j4*4+1]*inv, o[j4*4+2]*inv, o[j4*4+3]*inv };
            *(float4*)&dst[j4*4] = vv;
        }
    }
}

// ---------------------------------------------------------------------------
// Kernel 3: output GEMM. attn_out (32768 x 512) @ wout (512 x 512) -> d_out.
// ---------------------------------------------------------------------------
__global__ __launch_bounds__(256) void out_gemm(
    const float* __restrict__ a, const float* __restrict__ w, float* __restrict__ c)
{
    __shared__ float As[16][132];
    __shared__ float Bs[16][68];

    const int bm = blockIdx.x;
    const int bn = blockIdx.y;
    const int t  = threadIdx.x;
    const int tx = t & 15, ty = t >> 4;

    const int ar = t >> 2;
    const int ac = (t & 3) * 4;
    const int bk = t >> 4;
    const int bc = (t & 15) * 4;
    const int n0g = bn * 64;

    float acc[8][4] = {};

    for (int k0 = 0; k0 < 512; k0 += 16) {
        #pragma unroll
        for (int it = 0; it < 2; ++it) {
            int r = ar + it * 64;
            const float4 av = *(const float4*)&a[(size_t)(bm*128 + r)*512 + k0 + ac];
            As[ac+0][r] = av.x; As[ac+1][r] = av.y;
            As[ac+2][r] = av.z; As[ac+3][r] = av.w;
        }
        *(float4*)&Bs[bk][bc] = *(const float4*)&w[(size_t)(k0 + bk)*512 + n0g + bc];
        __syncthreads();

        #pragma unroll
        for (int kk = 0; kk < 16; ++kk) {
            float av2[8], bv[4];
            *(float4*)&av2[0] = *(const float4*)&As[kk][ty*8];
            *(float4*)&av2[4] = *(const float4*)&As[kk][ty*8+4];
            *(float4*)&bv[0] = *(const float4*)&Bs[kk][tx*4];
            #pragma unroll
            for (int i = 0; i < 8; ++i)
                #pragma unroll
                for (int j = 0; j < 4; ++j)
                    acc[i][j] = fmaf(av2[i], bv[j], acc[i][j]);
        }
        __syncthreads();
    }

    const int m0 = bm*128 + ty*8;
    const int n  = n0g + tx*4;
    #pragma unroll
    for (int i = 0; i < 8; ++i) {
        float4 v = { acc[i][0], acc[i][1], acc[i][2], acc[i][3] };
        *(float4*)&c[(size_t)(m0+i)*512 + n] = v;
    }
}

// ---------------------------------------------------------------------------
extern "C" void kernel_launch(void* const* d_in, const int* in_sizes, int n_in,
                              void* d_out, int out_size, void* d_ws, size_t ws_size,
                              hipStream_t stream)
{
    const float* x    = (const float*)d_in[0];
    const float* wq   = (const float*)d_in[1];
    const float* wkv  = (const float*)d_in[2];
    const float* wout = (const float*)d_in[3];
    const float* posw = (const float*)d_in[4];
    const float* posh = (const float*)d_in[5];
    float* out = (float*)d_out;

    // workspace: q (64MB) | k (64MB) | v (64MB) = 192 MB total.
    // attention output aliases the q buffer: each workgroup reads exactly its
    // own q slice into registers (barrier-ordered) before writing the same
    // slice; slices are disjoint across workgroups.
    float* qbuf = (float*)d_ws;
    float* kbuf = qbuf + (size_t)M_TOT * 512;
    float* vbuf = kbuf + (size_t)M_TOT * 512;

    dim3 g1(M_TOT/128, 1536/64);
    proj_gemm<<<g1, 256, 0, stream>>>(x, wq, wkv, qbuf, kbuf, vbuf);

    halo_attn<<<4096, 256, 0, stream>>>(qbuf, kbuf, vbuf, posw, posh, qbuf);

    dim3 g3(M_TOT/128, 512/64);
    out_gemm<<<g3, 256, 0, stream>>>(qbuf, wout, out);
}

// Round 2
// 1434.465 us; speedup vs baseline: 1.1270x; 1.1270x over previous
//
#include <hip/hip_runtime.h>
#include <math.h>

// Problem constants
#define NH    8
#define KD    64
#define BLK   8
#define HALO_ 4
#define KVK   16     // KV_KERNEL = BLOCK + 2*HALO
#define EMB_  512
#define B_    8
#define HW_   64
#define C_    512
#define HB_   8      // H / BLOCK
#define M_TOT (B_*HW_*HW_)   // 32768 pixels

// ---------------------------------------------------------------------------
// Kernel 1: fused projection GEMM.  x (32768 x 512) @ [wq | wkv] (512 x 1536)
// ---------------------------------------------------------------------------
__global__ __launch_bounds__(256) void proj_gemm(
    const float* __restrict__ x, const float* __restrict__ wq,
    const float* __restrict__ wkv,
    float* __restrict__ qbuf, float* __restrict__ kbuf, float* __restrict__ vbuf)
{
    __shared__ float As[16][132];   // transposed A tile [k][m], padded
    __shared__ float Bs[16][68];    // [k][n], padded

    const int bm = blockIdx.x;      // 256 row tiles
    const int bn = blockIdx.y;      // 24 col tiles
    const int t  = threadIdx.x;
    const int tx = t & 15, ty = t >> 4;

    const int n0g = bn * 64;
    const float* wsrc; int ldw, ncol;
    if (n0g < 512) { wsrc = wq;  ldw = 512;  ncol = n0g; }
    else           { wsrc = wkv; ldw = 1024; ncol = n0g - 512; }

    const int ar = t >> 2;          // A load: row within 64-row half
    const int ac = (t & 3) * 4;     // A load: k-col (float4)
    const int bk = t >> 4;          // B load: k row
    const int bc = (t & 15) * 4;    // B load: n col (float4)

    float acc[8][4] = {};

    for (int k0 = 0; k0 < 512; k0 += 16) {
        #pragma unroll
        for (int it = 0; it < 2; ++it) {
            int r = ar + it * 64;
            const float4 av = *(const float4*)&x[(size_t)(bm*128 + r)*512 + k0 + ac];
            As[ac+0][r] = av.x; As[ac+1][r] = av.y;
            As[ac+2][r] = av.z; As[ac+3][r] = av.w;
        }
        *(float4*)&Bs[bk][bc] = *(const float4*)&wsrc[(size_t)(k0 + bk)*ldw + ncol + bc];
        __syncthreads();

        #pragma unroll
        for (int kk = 0; kk < 16; ++kk) {
            float a[8], bv[4];
            *(float4*)&a[0] = *(const float4*)&As[kk][ty*8];
            *(float4*)&a[4] = *(const float4*)&As[kk][ty*8+4];
            *(float4*)&bv[0] = *(const float4*)&Bs[kk][tx*4];
            #pragma unroll
            for (int i = 0; i < 8; ++i)
                #pragma unroll
                for (int j = 0; j < 4; ++j)
                    acc[i][j] = fmaf(a[i], bv[j], acc[i][j]);
        }
        __syncthreads();
    }

    const float scale = 0.125f;     // KEY_DIM^-0.5
    const int m0 = bm*128 + ty*8;
    const int n  = n0g + tx*4;
    if (n0g < 512) {
        #pragma unroll
        for (int i = 0; i < 8; ++i) {
            float4 v = { acc[i][0]*scale, acc[i][1]*scale, acc[i][2]*scale, acc[i][3]*scale };
            *(float4*)&qbuf[(size_t)(m0+i)*512 + n] = v;
        }
    } else {
        const int jj = n - 512;
        const int head = jj >> 7;       // which head (128 ch per head in kv)
        const int dd = jj & 127;        // 0..63 key, 64..127 value
        float* dst = (dd < 64) ? kbuf : vbuf;
        const int d2 = dd & 63;
        #pragma unroll
        for (int i = 0; i < 8; ++i) {
            float4 v = { acc[i][0], acc[i][1], acc[i][2], acc[i][3] };
            *(float4*)&dst[(size_t)(m0+i)*512 + head*64 + d2] = v;
        }
    }
}

// ---------------------------------------------------------------------------
// Kernel 2: halo attention, 74 KB LDS -> 2 blocks/CU.
// One workgroup per (b, head, hb, wb) = 4096 blocks, 256 threads = 4 waves.
// Thread (q = t&63, g = t>>6). Wave g owns key quarter [g*64, g*64+64).
// Each wave keeps its quarter's softmax numerators in registers, computes a
// full-64-dim PV partial, then cross-wave reduces through the kv buffer
// (XOR-swizzled to dodge bank conflicts).
// ---------------------------------------------------------------------------
__global__ __launch_bounds__(256, 2) void halo_attn(
    const float* __restrict__ qbuf, const float* __restrict__ kbuf,
    const float* __restrict__ vbuf,
    const float* __restrict__ posw, const float* __restrict__ posh,
    float* __restrict__ obuf)
{
    __shared__ __align__(16) float kvbuf[256*64];  // 64 KB: pos tables, K, V, O-partials
    __shared__ float posq[64][33];                 // 8.4 KB
    __shared__ float red[4][64];                   // per-wave max
    __shared__ float red2[4][64];                  // per-wave sum

    const int wg = blockIdx.x;
    const int wb = wg & 7, hb = (wg >> 3) & 7, n = (wg >> 6) & 7, b = wg >> 9;
    const int t = threadIdx.x;
    const int q = t & 63, g = t >> 6;
    const int qi = q >> 3, qj = q & 7;

    float (*kv)[64]  = (float(*)[64])kvbuf;
    float (*pwT)[68] = (float(*)[68])kvbuf;              // 31 x 68 floats
    float (*phT)[68] = (float(*)[68])(kvbuf + 31*68);    // 31 x 68 floats

    // ---- stage pos tables transposed [idx][d] (overlaid on kv buffer) ----
    for (int j = t; j < 31*64; j += 256) {
        int idx = j >> 6, d = j & 63;
        pwT[idx][d] = posw[d*31 + idx];
        phT[idx][d] = posh[d*31 + idx];
    }

    // ---- load this thread's q row (already scaled) into registers ----
    float qr[64];
    {
        int y = hb*8 + qi, xx = wb*8 + qj;
        const float* src = &qbuf[((size_t)((b*64 + y)*64 + xx))*512 + n*64];
        #pragma unroll
        for (int d4 = 0; d4 < 16; ++d4)
            *(float4*)&qr[d4*4] = *(const float4*)&src[d4*4];
    }
    __syncthreads();   // B0: pos tables staged

    // ---- posq[q][c]: c<16 -> rel_w(kj), c>=16 -> rel_h(ki) ----
    #pragma unroll
    for (int j = 0; j < 8; ++j) {
        int c = g*8 + j;
        int idx = (c < 16) ? (c - qj + 15) : ((c - 16) - qi + 15);  // in [8,30]
        const float (*tab)[68] = (c < 16) ? pwT : phT;
        float a0 = 0.f, a1 = 0.f, a2 = 0.f, a3 = 0.f;
        #pragma unroll
        for (int d4 = 0; d4 < 16; ++d4) {
            float4 p4 = *(const float4*)&tab[idx][d4*4];
            a0 = fmaf(qr[d4*4+0], p4.x, a0);
            a1 = fmaf(qr[d4*4+1], p4.y, a1);
            a2 = fmaf(qr[d4*4+2], p4.z, a2);
            a3 = fmaf(qr[d4*4+3], p4.w, a3);
        }
        posq[q][c] = (a0 + a1) + (a2 + a3);
    }
    __syncthreads();   // B1: posq written, pos tables dead

    // ---- stage K tile (256 spatial x 64 dim), zero outside image ----
    const int sc = (t & 15) * 4;
    for (int it = 0; it < 16; ++it) {
        int s = it*16 + (t >> 4);
        int ki = s >> 4, kj = s & 15;
        int y = hb*8 - 4 + ki, xx = wb*8 - 4 + kj;
        float4 v = make_float4(0.f, 0.f, 0.f, 0.f);
        if ((unsigned)y < 64u && (unsigned)xx < 64u)
            v = *(const float4*)&kbuf[((size_t)((b*64 + y)*64 + xx))*512 + n*64 + sc];
        *(float4*)&kv[s][sc] = v;
    }
    __syncthreads();   // B2: K staged

    // ---- scores for this wave's 64 keys (4-acc chains + pos bias) ----
    float sreg[64];
    float mloc = -1e30f;
    #pragma unroll
    for (int i = 0; i < 64; ++i) {
        const int kk = g*64 + i;
        const int ki = kk >> 4, kj = kk & 15;
        float a0 = 0.f, a1 = 0.f, a2 = 0.f, a3 = 0.f;
        #pragma unroll
        for (int d4 = 0; d4 < 16; ++d4) {
            float4 kx = *(const float4*)&kv[kk][d4*4];
            a0 = fmaf(qr[d4*4+0], kx.x, a0);
            a1 = fmaf(qr[d4*4+1], kx.y, a1);
            a2 = fmaf(qr[d4*4+2], kx.z, a2);
            a3 = fmaf(qr[d4*4+3], kx.w, a3);
        }
        float s = (a0 + a1) + (a2 + a3) + posq[q][kj] + posq[q][16 + ki];
        sreg[i] = s;
        mloc = fmaxf(mloc, s);
    }
    red[g][q] = mloc;
    __syncthreads();   // B3: all K reads + maxes done

    const float m = fmaxf(fmaxf(red[0][q], red[1][q]), fmaxf(red[2][q], red[3][q]));
    float ssum = 0.f;
    #pragma unroll
    for (int i = 0; i < 64; ++i) {
        float p = __expf(sreg[i] - m);
        sreg[i] = p;
        ssum += p;
    }
    red2[g][q] = ssum;

    // ---- stage V tile over kv (K reads finished at B3) ----
    for (int it = 0; it < 16; ++it) {
        int s = it*16 + (t >> 4);
        int ki = s >> 4, kj = s & 15;
        int y = hb*8 - 4 + ki, xx = wb*8 - 4 + kj;
        float4 v = make_float4(0.f, 0.f, 0.f, 0.f);
        if ((unsigned)y < 64u && (unsigned)xx < 64u)
            v = *(const float4*)&vbuf[((size_t)((b*64 + y)*64 + xx))*512 + n*64 + sc];
        *(float4*)&kv[s][sc] = v;
    }
    __syncthreads();   // B4: V staged, red2 visible

    // ---- PV partial: wave g, its 64 keys, ALL 64 dims ----
    float o[64] = {};
    #pragma unroll
    for (int i = 0; i < 64; ++i) {
        const int kk = g*64 + i;
        const float p = sreg[i];
        #pragma unroll
        for (int d4 = 0; d4 < 16; ++d4) {
            float4 vv = *(const float4*)&kv[kk][d4*4];
            o[d4*4+0] = fmaf(p, vv.x, o[d4*4+0]);
            o[d4*4+1] = fmaf(p, vv.y, o[d4*4+1]);
            o[d4*4+2] = fmaf(p, vv.z, o[d4*4+2]);
            o[d4*4+3] = fmaf(p, vv.w, o[d4*4+3]);
        }
    }
    __syncthreads();   // B5: all V reads done, kv reusable

    // ---- write XOR-swizzled partials: row g*64+q, col (d4 ^ (q&15)) ----
    #pragma unroll
    for (int d4 = 0; d4 < 16; ++d4)
        *(float4*)&kv[g*64 + q][(d4 ^ (q & 15)) * 4] = *(float4*)&o[d4*4];
    __syncthreads();   // B6: partials visible

    // ---- cross-wave reduce + normalize + write; thread owns dims [g*16,g*16+16) ----
    const float inv = 1.f / (red2[0][q] + red2[1][q] + red2[2][q] + red2[3][q]);
    float of[16] = {};
    #pragma unroll
    for (int g2 = 0; g2 < 4; ++g2) {
        #pragma unroll
        for (int jj = 0; jj < 4; ++jj) {
            const int d4 = g*4 + jj;
            const float4 vv = *(const float4*)&kv[g2*64 + q][(d4 ^ (q & 15)) * 4];
            of[jj*4+0] += vv.x; of[jj*4+1] += vv.y;
            of[jj*4+2] += vv.z; of[jj*4+3] += vv.w;
        }
    }
    {
        int y = hb*8 + qi, xx = wb*8 + qj;
        float* dst = &obuf[((size_t)((b*64 + y)*64 + xx))*512 + n*64 + g*16];
        #pragma unroll
        for (int jj = 0; jj < 4; ++jj) {
            float4 w = { of[jj*4+0]*inv, of[jj*4+1]*inv, of[jj*4+2]*inv, of[jj*4+3]*inv };
            *(float4*)&dst[jj*4] = w;
        }
    }
}

// ---------------------------------------------------------------------------
// Kernel 3: output GEMM. attn_out (32768 x 512) @ wout (512 x 512) -> d_out.
// ---------------------------------------------------------------------------
__global__ __launch_bounds__(256) void out_gemm(
    const float* __restrict__ a, const float* __restrict__ w, float* __restrict__ c)
{
    __shared__ float As[16][132];
    __shared__ float Bs[16][68];

    const int bm = blockIdx.x;
    const int bn = blockIdx.y;
    const int t  = threadIdx.x;
    const int tx = t & 15, ty = t >> 4;

    const int ar = t >> 2;
    const int ac = (t & 3) * 4;
    const int bk = t >> 4;
    const int bc = (t & 15) * 4;
    const int n0g = bn * 64;

    float acc[8][4] = {};

    for (int k0 = 0; k0 < 512; k0 += 16) {
        #pragma unroll
        for (int it = 0; it < 2; ++it) {
            int r = ar + it * 64;
            const float4 av = *(const float4*)&a[(size_t)(bm*128 + r)*512 + k0 + ac];
            As[ac+0][r] = av.x; As[ac+1][r] = av.y;
            As[ac+2][r] = av.z; As[ac+3][r] = av.w;
        }
        *(float4*)&Bs[bk][bc] = *(const float4*)&w[(size_t)(k0 + bk)*512 + n0g + bc];
        __syncthreads();

        #pragma unroll
        for (int kk = 0; kk < 16; ++kk) {
            float av2[8], bv[4];
            *(float4*)&av2[0] = *(const float4*)&As[kk][ty*8];
            *(float4*)&av2[4] = *(const float4*)&As[kk][ty*8+4];
            *(float4*)&bv[0] = *(const float4*)&Bs[kk][tx*4];
            #pragma unroll
            for (int i = 0; i < 8; ++i)
                #pragma unroll
                for (int j = 0; j < 4; ++j)
                    acc[i][j] = fmaf(av2[i], bv[j], acc[i][j]);
        }
        __syncthreads();
    }

    const int m0 = bm*128 + ty*8;
    const int n  = n0g + tx*4;
    #pragma unroll
    for (int i = 0; i < 8; ++i) {
        float4 v = { acc[i][0], acc[i][1], acc[i][2], acc[i][3] };
        *(float4*)&c[(size_t)(m0+i)*512 + n] = v;
    }
}

// ---------------------------------------------------------------------------
extern "C" void kernel_launch(void* const* d_in, const int* in_sizes, int n_in,
                              void* d_out, int out_size, void* d_ws, size_t ws_size,
                              hipStream_t stream)
{
    const float* x    = (const float*)d_in[0];
    const float* wq   = (const float*)d_in[1];
    const float* wkv  = (const float*)d_in[2];
    const float* wout = (const float*)d_in[3];
    const float* posw = (const float*)d_in[4];
    const float* posh = (const float*)d_in[5];
    float* out = (float*)d_out;

    // workspace: q (64MB) | k (64MB) | v (64MB) = 192 MB total.
    // attention output aliases the q buffer: each workgroup reads exactly its
    // own q slice (phase 1, pre-barrier) before writing the same slice at the
    // end; slices are disjoint across workgroups.
    float* qbuf = (float*)d_ws;
    float* kbuf = qbuf + (size_t)M_TOT * 512;
    float* vbuf = kbuf + (size_t)M_TOT * 512;

    dim3 g1(M_TOT/128, 1536/64);
    proj_gemm<<<g1, 256, 0, stream>>>(x, wq, wkv, qbuf, kbuf, vbuf);

    halo_attn<<<4096, 256, 0, stream>>>(qbuf, kbuf, vbuf, posw, posh, qbuf);

    dim3 g3(M_TOT/128, 512/64);
    out_gemm<<<g3, 256, 0, stream>>>(qbuf, wout, out);
}

// Round 3
// 402.329 us; speedup vs baseline: 4.0181x; 3.5654x over previous
//
#include <hip/hip_runtime.h>
#include <hip/hip_fp16.h>
#include <math.h>

typedef _Float16 f16x8 __attribute__((ext_vector_type(8)));
typedef float    f32x4 __attribute__((ext_vector_type(4)));

#define M_TOT 32768   // 8*64*64 pixels

// ---------------------------------------------------------------------------
// async global->LDS, 16B per lane. LDS dest = wave-uniform base + lane*16.
// ---------------------------------------------------------------------------
__device__ __forceinline__ void gload16(const void* g, void* l) {
    __builtin_amdgcn_global_load_lds(
        (const __attribute__((address_space(1))) unsigned int*)g,
        (__attribute__((address_space(3))) unsigned int*)l, 16, 0, 0);
}

__device__ __forceinline__ f32x4 mfma16(f16x8 a, f16x8 b, f32x4 c) {
    return __builtin_amdgcn_mfma_f32_16x16x32_f16(a, b, c, 0, 0, 0);
}

// ---------------------------------------------------------------------------
// x (fp32) -> fp16
// ---------------------------------------------------------------------------
__global__ __launch_bounds__(256) void conv_x(const float* __restrict__ x,
                                              __half* __restrict__ y) {
    const size_t i = ((size_t)blockIdx.x * 256 + threadIdx.x) * 8;
    float4 a = *(const float4*)&x[i];
    float4 b = *(const float4*)&x[i + 4];
    __half2 h[4];
    h[0] = __floats2half2_rn(a.x, a.y);
    h[1] = __floats2half2_rn(a.z, a.w);
    h[2] = __floats2half2_rn(b.x, b.y);
    h[3] = __floats2half2_rn(b.z, b.w);
    *(float4*)&y[i] = *(float4*)h;
}

// ---------------------------------------------------------------------------
// weights -> fp16, transposed to [n][k]; q-scale 0.125 folded into wq.
// wT: rows 0..511 = wq^T*0.125, rows 512..1535 = wkv^T. woT = wout^T.
// ---------------------------------------------------------------------------
__global__ __launch_bounds__(256) void conv_w(const float* __restrict__ wq,
                                              const float* __restrict__ wkv,
                                              const float* __restrict__ wout,
                                              __half* __restrict__ wT,
                                              __half* __restrict__ woT) {
    const int id = blockIdx.x * 256 + threadIdx.x;   // < 2048*512
    const int nr = id >> 9, k = id & 511;
    if (nr < 512) {
        wT[(size_t)nr * 512 + k]  = __float2half(wq[k * 512 + nr] * 0.125f);
    } else if (nr < 1536) {
        wT[(size_t)nr * 512 + k]  = __float2half(wkv[k * 1024 + (nr - 512)]);
    } else {
        woT[(size_t)(nr - 1536) * 512 + k] = __float2half(wout[k * 512 + (nr - 1536)]);
    }
}

// ---------------------------------------------------------------------------
// fp16 MFMA GEMM, m97 structure: BM=BN=128, BK=32, 4 waves (64x64 each,
// 4x4 16x16x32 frags), single-buffered LDS staged via global_load_lds x16B.
// A: [M][512] fp16 row-major. Bt: [N][512] fp16 (transposed weights).
// MODE 0: proj epilogue (split q/k/v fp16).  MODE 1: fp32 store to outf.
// ---------------------------------------------------------------------------
template <int MODE>
__global__ __launch_bounds__(256) void mfma_gemm(
    const __half* __restrict__ A, const __half* __restrict__ Bt,
    __half* __restrict__ q16, __half* __restrict__ k16, __half* __restrict__ v16,
    float* __restrict__ outf)
{
    __shared__ _Float16 As[128 * 32];   // 8 KB
    __shared__ _Float16 Bs[128 * 32];   // 8 KB

    const int t = threadIdx.x;
    const int l = t & 63, w = t >> 6;
    const int wr = w >> 1, wc = w & 1;
    const int bm = blockIdx.x, bn = blockIdx.y;

    f32x4 zero = {0.f, 0.f, 0.f, 0.f};
    f32x4 acc[4][4];
    #pragma unroll
    for (int i = 0; i < 4; ++i)
        #pragma unroll
        for (int j = 0; j < 4; ++j) acc[i][j] = zero;

    // staging geometry: region ri = w*2+j covers rows [ri*16, ri*16+16)
    const int srow = w * 32 + (l >> 2);          // row for call j=0
    const int sch  = (l & 3) * 8;                // k-chunk (8 halves = 16B)
    const size_t abase = (size_t)(bm * 128 + srow) * 512 + sch;
    const size_t bbase = (size_t)(bn * 128 + srow) * 512 + sch;
    _Float16* ldsA0 = &As[(w * 2 + 0) * 512];
    _Float16* ldsA1 = &As[(w * 2 + 1) * 512];
    _Float16* ldsB0 = &Bs[(w * 2 + 0) * 512];
    _Float16* ldsB1 = &Bs[(w * 2 + 1) * 512];

    const int lr = l & 15, lk = (l >> 4) * 8;

    for (int k0 = 0; k0 < 512; k0 += 32) {
        gload16(A  + abase + k0,            ldsA0);
        gload16(A  + abase + 16 * 512 + k0, ldsA1);
        gload16(Bt + bbase + k0,            ldsB0);
        gload16(Bt + bbase + 16 * 512 + k0, ldsB1);
        __syncthreads();

        f16x8 af[4], bf[4];
        #pragma unroll
        for (int i = 0; i < 4; ++i)
            af[i] = *(const f16x8*)&As[(wr * 64 + i * 16 + lr) * 32 + lk];
        #pragma unroll
        for (int j = 0; j < 4; ++j)
            bf[j] = *(const f16x8*)&Bs[(wc * 64 + j * 16 + lr) * 32 + lk];
        #pragma unroll
        for (int i = 0; i < 4; ++i)
            #pragma unroll
            for (int j = 0; j < 4; ++j)
                acc[i][j] = mfma16(af[i], bf[j], acc[i][j]);
        __syncthreads();
    }

    // epilogue: C/D frag mapping col = lane&15, row = (lane>>4)*4 + r
    const int lq = l >> 4;
    #pragma unroll
    for (int i = 0; i < 4; ++i) {
        #pragma unroll
        for (int j = 0; j < 4; ++j) {
            #pragma unroll
            for (int r = 0; r < 4; ++r) {
                const int row = bm * 128 + wr * 64 + i * 16 + lq * 4 + r;
                const int col = bn * 128 + wc * 64 + j * 16 + lr;
                const float vv = acc[i][j][r];
                if (MODE == 1) {
                    outf[(size_t)row * 512 + col] = vv;
                } else {
                    if (col < 512) {
                        q16[(size_t)row * 512 + col] = __float2half(vv);
                    } else {
                        const int c2 = col - 512;
                        const int head = c2 >> 7, dd = c2 & 127;
                        __half* dst = (dd < 64) ? k16 : v16;
                        dst[(size_t)row * 512 + head * 64 + (dd & 63)] = __float2half(vv);
                    }
                }
            }
        }
    }
}

// ---------------------------------------------------------------------------
// halo attention, fp16 packed-VALU. 4096 blocks x 256 threads (4 waves).
// thread = (q = t&63, g = t>>6); wave g owns key quarter [g*64, g*64+64).
// LDS 76 KB -> 2 blocks/CU; no per-thread 64-deep arrays -> no spill.
// ---------------------------------------------------------------------------
__global__ __launch_bounds__(256, 2) void halo_attn(
    const __half* __restrict__ qbuf, const __half* __restrict__ kbuf,
    const __half* __restrict__ vbuf,
    const float* __restrict__ posw, const float* __restrict__ posh,
    __half* __restrict__ obuf)
{
    __shared__ __half kvs[256 * 64];   // 32 KB: pos tables overlay, then K, then V
    __shared__ __half sp[64][258];     // 33 KB: scores -> probabilities
    __shared__ float posq[64][33];     // 8.4 KB
    __shared__ float red[4][64];       // per-wave max
    __shared__ float red2[4][64];      // per-wave sum

    const int wg = blockIdx.x;
    const int wb = wg & 7, hb = (wg >> 3) & 7, n = (wg >> 6) & 7, b = wg >> 9;
    const int t = threadIdx.x;
    const int q = t & 63, g = t >> 6;
    const int qi = q >> 3, qj = q & 7;

    __half* pwT = kvs;                 // [31][72] fp16
    __half* phT = kvs + 31 * 72;

    // ---- stage pos tables (transposed [idx][d], fp16) ----
    for (int j5 = t; j5 < 31 * 64; j5 += 256) {
        const int idx = j5 >> 6, d = j5 & 63;
        pwT[idx * 72 + d] = __float2half(posw[d * 31 + idx]);
        phT[idx * 72 + d] = __float2half(posh[d * 31 + idx]);
    }

    // ---- q row (scaled) into half2 registers ----
    const int pix = (b * 64 + hb * 8 + qi) * 64 + wb * 8 + qj;
    __half2 qh[32];
    {
        const __half* qsrc = qbuf + (size_t)pix * 512 + n * 64;
        #pragma unroll
        for (int r = 0; r < 8; ++r) {
            float4 f = *(const float4*)&qsrc[r * 8];
            const __half2* qp = (const __half2*)&f;
            qh[r * 4 + 0] = qp[0]; qh[r * 4 + 1] = qp[1];
            qh[r * 4 + 2] = qp[2]; qh[r * 4 + 3] = qp[3];
        }
    }
    __syncthreads();   // B0: pos tables staged

    // ---- posq[q][c]: c<16 -> rel_w(kj), c>=16 -> rel_h(ki) ----
    #pragma unroll
    for (int j = 0; j < 8; ++j) {
        const int c = g * 8 + j;
        const int idx = (c < 16) ? (c - qj + 15) : ((c - 16) - qi + 15);  // [8,30]
        const __half* tab = ((c < 16) ? pwT : phT) + idx * 72;
        __half2 a0 = __floats2half2_rn(0.f, 0.f), a1 = a0, a2 = a0, a3 = a0;
        #pragma unroll
        for (int d8 = 0; d8 < 8; ++d8) {
            float4 tv = *(const float4*)&tab[d8 * 8];
            const __half2* tp = (const __half2*)&tv;
            a0 = __hfma2(qh[d8 * 4 + 0], tp[0], a0);
            a1 = __hfma2(qh[d8 * 4 + 1], tp[1], a1);
            a2 = __hfma2(qh[d8 * 4 + 2], tp[2], a2);
            a3 = __hfma2(qh[d8 * 4 + 3], tp[3], a3);
        }
        const __half2 s2 = __hadd2(__hadd2(a0, a1), __hadd2(a2, a3));
        posq[q][c] = __low2float(s2) + __high2float(s2);
    }
    __syncthreads();   // B1: posq done, pos tables dead

    // ---- stage K tile (256 rows x 64 halves), zero outside image ----
    #pragma unroll
    for (int it = 0; it < 8; ++it) {
        const int cid = it * 256 + t;           // 2048 16B-chunks
        const int row = cid >> 3, ch = cid & 7;
        const int ki = row >> 4, kj = row & 15;
        const int y = hb * 8 - 4 + ki, xx = wb * 8 - 4 + kj;
        float4 v = make_float4(0.f, 0.f, 0.f, 0.f);
        if ((unsigned)y < 64u && (unsigned)xx < 64u)
            v = *(const float4*)&kbuf[((size_t)((b * 64 + y) * 64 + xx)) * 512 + n * 64 + ch * 8];
        *(float4*)&kvs[row * 64 + ch * 8] = v;
    }
    __syncthreads();   // B2: K staged

    // ---- scores for this wave's 64 keys (packed fp16 dot + pos bias) ----
    float mloc = -1e30f;
    #pragma unroll 4
    for (int i = 0; i < 64; ++i) {
        const int kk = g * 64 + i;
        const __half* krow = &kvs[kk * 64];
        __half2 a0 = __floats2half2_rn(0.f, 0.f), a1 = a0, a2 = a0, a3 = a0;
        #pragma unroll
        for (int d8 = 0; d8 < 8; ++d8) {
            float4 kf = *(const float4*)&krow[d8 * 8];
            const __half2* kp = (const __half2*)&kf;
            a0 = __hfma2(qh[d8 * 4 + 0], kp[0], a0);
            a1 = __hfma2(qh[d8 * 4 + 1], kp[1], a1);
            a2 = __hfma2(qh[d8 * 4 + 2], kp[2], a2);
            a3 = __hfma2(qh[d8 * 4 + 3], kp[3], a3);
        }
        const __half2 s2 = __hadd2(__hadd2(a0, a1), __hadd2(a2, a3));
        float s = __low2float(s2) + __high2float(s2)
                + posq[q][kk & 15] + posq[q][16 + (kk >> 4)];
        sp[q][kk] = __float2half(s);
        mloc = fmaxf(mloc, s);
    }
    red[g][q] = mloc;
    __syncthreads();   // B3: all K reads + score writes + maxes done

    // ---- softmax numerators (in place in sp), per-wave sums ----
    const float m = fmaxf(fmaxf(red[0][q], red[1][q]), fmaxf(red[2][q], red[3][q]));
    float ssum = 0.f;
    #pragma unroll 8
    for (int i = 0; i < 64; ++i) {
        const int kk = g * 64 + i;
        const float p = __expf(__half2float(sp[q][kk]) - m);
        sp[q][kk] = __float2half(p);
        ssum += p;
    }
    red2[g][q] = ssum;

    // ---- stage V tile over kvs (kvs K-reads all done at B3) ----
    #pragma unroll
    for (int it = 0; it < 8; ++it) {
        const int cid = it * 256 + t;
        const int row = cid >> 3, ch = cid & 7;
        const int ki = row >> 4, kj = row & 15;
        const int y = hb * 8 - 4 + ki, xx = wb * 8 - 4 + kj;
        float4 v = make_float4(0.f, 0.f, 0.f, 0.f);
        if ((unsigned)y < 64u && (unsigned)xx < 64u)
            v = *(const float4*)&vbuf[((size_t)((b * 64 + y) * 64 + xx)) * 512 + n * 64 + ch * 8];
        *(float4*)&kvs[row * 64 + ch * 8] = v;
    }
    __syncthreads();   // B4: V staged, sp probabilities + red2 visible

    // ---- PV: thread (q,g) owns output dims [g*16, g*16+16) ----
    const float inv = 1.f / (red2[0][q] + red2[1][q] + red2[2][q] + red2[3][q]);
    __half2 o2[8];
    #pragma unroll
    for (int j = 0; j < 8; ++j) o2[j] = __floats2half2_rn(0.f, 0.f);
    #pragma unroll 4
    for (int kk = 0; kk < 256; ++kk) {
        const __half2 pp = __half2half2(sp[q][kk]);
        const __half* vrow = &kvs[kk * 64 + g * 16];
        float4 v0 = *(const float4*)&vrow[0];
        float4 v1 = *(const float4*)&vrow[8];
        const __half2* p0 = (const __half2*)&v0;
        const __half2* p1 = (const __half2*)&v1;
        o2[0] = __hfma2(pp, p0[0], o2[0]); o2[1] = __hfma2(pp, p0[1], o2[1]);
        o2[2] = __hfma2(pp, p0[2], o2[2]); o2[3] = __hfma2(pp, p0[3], o2[3]);
        o2[4] = __hfma2(pp, p1[0], o2[4]); o2[5] = __hfma2(pp, p1[1], o2[5]);
        o2[6] = __hfma2(pp, p1[2], o2[6]); o2[7] = __hfma2(pp, p1[3], o2[7]);
    }
    {
        __half ov[16];
        #pragma unroll
        for (int j = 0; j < 8; ++j) {
            ov[2 * j + 0] = __float2half(__low2float(o2[j]) * inv);
            ov[2 * j + 1] = __float2half(__high2float(o2[j]) * inv);
        }
        __half* dst = obuf + (size_t)pix * 512 + n * 64 + g * 16;
        *(float4*)&dst[0] = *(float4*)&ov[0];
        *(float4*)&dst[8] = *(float4*)&ov[8];
    }
}

// ---------------------------------------------------------------------------
extern "C" void kernel_launch(void* const* d_in, const int* in_sizes, int n_in,
                              void* d_out, int out_size, void* d_ws, size_t ws_size,
                              hipStream_t stream)
{
    const float* x    = (const float*)d_in[0];
    const float* wq   = (const float*)d_in[1];
    const float* wkv  = (const float*)d_in[2];
    const float* wout = (const float*)d_in[3];
    const float* posw = (const float*)d_in[4];
    const float* posh = (const float*)d_in[5];
    float* out = (float*)d_out;

    // fp16 workspace layout (170 MB total)
    __half* x16  = (__half*)d_ws;                          // 32 MB
    __half* wT   = x16 + (size_t)M_TOT * 512;              // 1.5 MB (1536x512)
    __half* woT  = wT  + (size_t)1536 * 512;               // 0.5 MB (512x512)
    __half* q16  = woT + (size_t)512 * 512;                // 32 MB
    __half* k16  = q16 + (size_t)M_TOT * 512;              // 32 MB
    __half* v16  = k16 + (size_t)M_TOT * 512;              // 32 MB
    __half* o16  = v16 + (size_t)M_TOT * 512;              // 32 MB

    conv_x<<<(M_TOT * 512) / (256 * 8), 256, 0, stream>>>(x, x16);
    conv_w<<<(2048 * 512) / 256, 256, 0, stream>>>(wq, wkv, wout, wT, woT);

    dim3 g1(M_TOT / 128, 12);
    mfma_gemm<0><<<g1, 256, 0, stream>>>(x16, wT, q16, k16, v16, nullptr);

    halo_attn<<<4096, 256, 0, stream>>>(q16, k16, v16, posw, posh, o16);

    dim3 g3(M_TOT / 128, 4);
    mfma_gemm<1><<<g3, 256, 0, stream>>>(o16, woT, nullptr, nullptr, nullptr, out);
}

// Round 5
// 267.984 us; speedup vs baseline: 6.0325x; 1.5013x over previous
//
#include <hip/hip_runtime.h>
#include <hip/hip_fp16.h>
#include <math.h>

typedef _Float16 f16x8 __attribute__((ext_vector_type(8)));
typedef _Float16 f16x4 __attribute__((ext_vector_type(4)));
typedef float    f32x4 __attribute__((ext_vector_type(4)));

#define M_TOT 32768   // 8*64*64 pixels

// ---------------------------------------------------------------------------
// async global->LDS, 16B per lane. LDS dest = wave-uniform base + lane*16.
// ---------------------------------------------------------------------------
__device__ __forceinline__ void gload16(const void* g, void* l) {
    __builtin_amdgcn_global_load_lds(
        (const __attribute__((address_space(1))) unsigned int*)g,
        (__attribute__((address_space(3))) unsigned int*)l, 16, 0, 0);
}

// ---------------------------------------------------------------------------
// x (fp32) -> fp16
// ---------------------------------------------------------------------------
__global__ __launch_bounds__(256) void conv_x(const float* __restrict__ x,
                                              __half* __restrict__ y) {
    const size_t i = ((size_t)blockIdx.x * 256 + threadIdx.x) * 8;
    float4 a = *(const float4*)&x[i];
    float4 b = *(const float4*)&x[i + 4];
    __half2 h[4];
    h[0] = __floats2half2_rn(a.x, a.y);
    h[1] = __floats2half2_rn(a.z, a.w);
    h[2] = __floats2half2_rn(b.x, b.y);
    h[3] = __floats2half2_rn(b.z, b.w);
    *(float4*)&y[i] = *(float4*)h;
}

// ---------------------------------------------------------------------------
// weights -> fp16, transposed to [n][k]; q-scale 0.125 folded into wq.
// ---------------------------------------------------------------------------
__global__ __launch_bounds__(256) void conv_w(const float* __restrict__ wq,
                                              const float* __restrict__ wkv,
                                              const float* __restrict__ wout,
                                              __half* __restrict__ wT,
                                              __half* __restrict__ woT) {
    const int id = blockIdx.x * 256 + threadIdx.x;   // < 2048*512
    const int nr = id >> 9, k = id & 511;
    if (nr < 512) {
        wT[(size_t)nr * 512 + k]  = __float2half(wq[k * 512 + nr] * 0.125f);
    } else if (nr < 1536) {
        wT[(size_t)nr * 512 + k]  = __float2half(wkv[k * 1024 + (nr - 512)]);
    } else {
        woT[(size_t)(nr - 1536) * 512 + k] = __float2half(wout[k * 512 + (nr - 1536)]);
    }
}

// ---------------------------------------------------------------------------
// fp16 MFMA GEMM (m97 structure), BM=BN=128, BK=32, 4 waves.
// MODE 0: proj epilogue (split q/k/v fp16). MODE 1: fp32 store to outf.
// ---------------------------------------------------------------------------
template <int MODE>
__global__ __launch_bounds__(256) void mfma_gemm(
    const __half* __restrict__ A, const __half* __restrict__ Bt,
    __half* __restrict__ q16, __half* __restrict__ k16, __half* __restrict__ v16,
    float* __restrict__ outf)
{
    __shared__ _Float16 As[128 * 32];
    __shared__ _Float16 Bs[128 * 32];

    const int t = threadIdx.x;
    const int l = t & 63, w = t >> 6;
    const int wr = w >> 1, wc = w & 1;
    const int bm = blockIdx.x, bn = blockIdx.y;

    f32x4 zero = {0.f, 0.f, 0.f, 0.f};
    f32x4 acc[4][4];
    #pragma unroll
    for (int i = 0; i < 4; ++i)
        #pragma unroll
        for (int j = 0; j < 4; ++j) acc[i][j] = zero;

    const int srow = w * 32 + (l >> 2);
    const int sch  = (l & 3) * 8;
    const size_t abase = (size_t)(bm * 128 + srow) * 512 + sch;
    const size_t bbase = (size_t)(bn * 128 + srow) * 512 + sch;
    _Float16* ldsA0 = &As[(w * 2 + 0) * 512];
    _Float16* ldsA1 = &As[(w * 2 + 1) * 512];
    _Float16* ldsB0 = &Bs[(w * 2 + 0) * 512];
    _Float16* ldsB1 = &Bs[(w * 2 + 1) * 512];

    const int lr = l & 15, lk = (l >> 4) * 8;

    for (int k0 = 0; k0 < 512; k0 += 32) {
        gload16(A  + abase + k0,            ldsA0);
        gload16(A  + abase + 16 * 512 + k0, ldsA1);
        gload16(Bt + bbase + k0,            ldsB0);
        gload16(Bt + bbase + 16 * 512 + k0, ldsB1);
        __syncthreads();

        f16x8 af[4], bf[4];
        #pragma unroll
        for (int i = 0; i < 4; ++i)
            af[i] = *(const f16x8*)&As[(wr * 64 + i * 16 + lr) * 32 + lk];
        #pragma unroll
        for (int j = 0; j < 4; ++j)
            bf[j] = *(const f16x8*)&Bs[(wc * 64 + j * 16 + lr) * 32 + lk];
        #pragma unroll
        for (int i = 0; i < 4; ++i)
            #pragma unroll
            for (int j = 0; j < 4; ++j)
                acc[i][j] = __builtin_amdgcn_mfma_f32_16x16x32_f16(af[i], bf[j], acc[i][j], 0, 0, 0);
        __syncthreads();
    }

    const int lq = l >> 4;
    #pragma unroll
    for (int i = 0; i < 4; ++i) {
        #pragma unroll
        for (int j = 0; j < 4; ++j) {
            #pragma unroll
            for (int r = 0; r < 4; ++r) {
                const int row = bm * 128 + wr * 64 + i * 16 + lq * 4 + r;
                const int col = bn * 128 + wc * 64 + j * 16 + lr;
                const float vv = acc[i][j][r];
                if (MODE == 1) {
                    outf[(size_t)row * 512 + col] = vv;
                } else {
                    if (col < 512) {
                        q16[(size_t)row * 512 + col] = __float2half(vv);
                    } else {
                        const int c2 = col - 512;
                        const int head = c2 >> 7, dd = c2 & 127;
                        __half* dst = (dd < 64) ? k16 : v16;
                        dst[(size_t)row * 512 + head * 64 + (dd & 63)] = __float2half(vv);
                    }
                }
            }
        }
    }
}

// ---------------------------------------------------------------------------
// V transpose: v16 [b*4096+px][n*64+d] -> vT [(b*8+n)*64+d][4096 px]
// ---------------------------------------------------------------------------
__global__ __launch_bounds__(256) void transpose_v(const __half* __restrict__ v16,
                                                   __half* __restrict__ vT) {
    __shared__ __half tile[64][72];
    const int wg = blockIdx.x;
    const int tl = wg & 63, n = (wg >> 6) & 7, b = wg >> 9;
    const int px0 = tl * 64;
    const int t = threadIdx.x;

    #pragma unroll
    for (int i = 0; i < 2; ++i) {
        const int c = i * 256 + t;           // 512 chunks of 8 halves
        const int px = c >> 3, dch = c & 7;
        float4 v = *(const float4*)(v16 + ((size_t)(b * 4096 + px0 + px)) * 512 + n * 64 + dch * 8);
        *(float4*)&tile[px][dch * 8] = v;
    }
    __syncthreads();
    const int d = t & 63, pc = t >> 6;       // 4 chunks of 16 px
    __half ov[16];
    #pragma unroll
    for (int j = 0; j < 16; ++j) ov[j] = tile[pc * 16 + j][d];
    __half* dst = vT + ((size_t)((b * 8 + n) * 64 + d)) * 4096 + px0 + pc * 16;
    *(float4*)&dst[0] = *(float4*)&ov[0];
    *(float4*)&dst[8] = *(float4*)&ov[8];
}

// ---------------------------------------------------------------------------
// MFMA halo attention. 4096 blocks x 4 waves; wave g owns key quarter
// [g*64, g*64+64) for QK^T/softmax and dim quarter [g*16,g*16+16) for PV.
// ---------------------------------------------------------------------------
__global__ __launch_bounds__(256, 2) void halo_attn(
    const __half* __restrict__ qbuf, const __half* __restrict__ kbuf,
    const __half* __restrict__ vT,
    const float* __restrict__ posw, const float* __restrict__ posh,
    const __half* __restrict__ zp,
    __half* __restrict__ obuf)
{
    __shared__ __align__(16) char KP[64 * 536];   // 34304 B
    __shared__ __align__(16) char VTl[64 * 536];  // 34304 B
    __shared__ float posq[64][33];
    __shared__ float red[4][64];
    __shared__ float red2[4][64];

    const int wg = blockIdx.x;
    const int wb = wg & 7, hb = (wg >> 3) & 7, n = (wg >> 6) & 7, b = wg >> 9;
    const int t = threadIdx.x;
    const int l = t & 63, g = t >> 6;
    const int hi = l >> 4, c15 = l & 15;

    // ---- issue V^T tile loads into regs (16 x 8B), bounds -> zero page ----
    const int kiv = l >> 2, cxv = t & 3;
    const int yv = hb * 8 - 4 + kiv;
    const int xv0 = wb * 8 - 4 + cxv * 4;
    const bool okv = ((unsigned)yv < 64u) && ((unsigned)xv0 < 64u);
    const __half* vbase = vT + ((size_t)((b * 8 + n) * 64)) * 4096;
    const int voff = yv * 64 + xv0;
    uint2 vreg[16];
    #pragma unroll
    for (int m = 0; m < 16; ++m) {
        const int d = m * 4 + g;
        const __half* p = okv ? (vbase + (size_t)d * 4096 + voff) : zp;
        vreg[m] = *(const uint2*)p;
    }

    // ---- stage pos tables transposed [idx][d] fp16 (overlay KP) ----
    __half* pwT = (__half*)KP;            // [31][72]
    __half* phT = pwT + 31 * 72;
    for (int j5 = t; j5 < 31 * 64; j5 += 256) {
        const int idx = j5 >> 6, d = j5 & 63;
        pwT[idx * 72 + d] = __float2half(posw[d * 31 + idx]);
        phT[idx * 72 + d] = __float2half(posh[d * 31 + idx]);
    }

    // ---- q row for posq (thread = q-row l, wave g computes c = g*8..+8) ----
    const int qrow = l;
    const int pixq = (b * 64 + hb * 8 + (qrow >> 3)) * 64 + wb * 8 + (qrow & 7);
    __half2 qh[32];
    {
        const __half* qsrc = qbuf + (size_t)pixq * 512 + n * 64;
        #pragma unroll
        for (int r = 0; r < 8; ++r) {
            float4 f = *(const float4*)&qsrc[r * 8];
            const __half2* qp = (const __half2*)&f;
            qh[r * 4 + 0] = qp[0]; qh[r * 4 + 1] = qp[1];
            qh[r * 4 + 2] = qp[2]; qh[r * 4 + 3] = qp[3];
        }
    }
    __syncthreads();   // B0: pos tables staged

    #pragma unroll
    for (int j = 0; j < 8; ++j) {
        const int c = g * 8 + j;
        const int idx = (c < 16) ? (c - (qrow & 7) + 15) : ((c - 16) - (qrow >> 3) + 15);
        const __half* tab = ((c < 16) ? pwT : phT) + idx * 72;
        __half2 a0 = __floats2half2_rn(0.f, 0.f), a1 = a0, a2 = a0, a3 = a0;
        #pragma unroll
        for (int d8 = 0; d8 < 8; ++d8) {
            float4 tv = *(const float4*)&tab[d8 * 8];
            const __half2* tp = (const __half2*)&tv;
            a0 = __hfma2(qh[d8 * 4 + 0], tp[0], a0);
            a1 = __hfma2(qh[d8 * 4 + 1], tp[1], a1);
            a2 = __hfma2(qh[d8 * 4 + 2], tp[2], a2);
            a3 = __hfma2(qh[d8 * 4 + 3], tp[3], a3);
        }
        const __half2 s2 = __hadd2(__hadd2(a0, a1), __hadd2(a2, a3));
        posq[qrow][c] = __low2float(s2) + __high2float(s2);
    }
    __syncthreads();   // B1: posq done, pos tables dead -> K region free

    // ---- stage K via global_load_lds, source pre-swizzled (^ (row&7)<<4) ----
    #pragma unroll
    for (int it = 0; it < 8; ++it) {
        const int cid = it * 256 + t;
        const int S = cid * 16;                       // linear LDS byte
        const int row = S >> 7;                       // key 0..255
        const int d0h = (((S & 127) >> 4) ^ (row & 7)) * 8;   // halves
        const int ky = hb * 8 - 4 + (row >> 4);
        const int kx = wb * 8 - 4 + (row & 15);
        const bool ok = ((unsigned)ky < 64u) && ((unsigned)kx < 64u);
        const __half* src = ok ? (kbuf + ((size_t)((b * 64 + ky) * 64 + kx)) * 512 + n * 64 + d0h)
                               : zp;
        gload16(src, KP + (it * 256 + g * 64) * 16);
    }

    // ---- write V^T tile to LDS [d][268] ----
    #pragma unroll
    for (int m = 0; m < 16; ++m) {
        const int d = m * 4 + g;
        *(uint2*)(VTl + d * 536 + (kiv * 16 + cxv * 4) * 2) = vreg[m];
    }

    // ---- Q fragments (B-operand of 16x16x32): qreg[qf][dc] ----
    f16x8 qreg[4][2];
    #pragma unroll
    for (int qf = 0; qf < 4; ++qf) {
        const int q = qf * 16 + c15;
        const size_t pix = (size_t)((b * 64 + hb * 8 + (q >> 3)) * 64 + wb * 8 + (q & 7));
        #pragma unroll
        for (int dc = 0; dc < 2; ++dc)
            qreg[qf][dc] = *(const f16x8*)(qbuf + pix * 512 + n * 64 + dc * 32 + hi * 8);
    }
    __syncthreads();   // B2: K + V^T staged

    // ---- QK^T: S^T frags, A=K (swizzled LDS, wave g's quarter), B=Q regs ----
    f32x4 accs[4][4];
    #pragma unroll
    for (int kf = 0; kf < 4; ++kf)
        #pragma unroll
        for (int qf = 0; qf < 4; ++qf) accs[kf][qf] = (f32x4){0.f, 0.f, 0.f, 0.f};

    #pragma unroll
    for (int kf = 0; kf < 4; ++kf) {
        const int row = g * 64 + kf * 16 + c15;   // FIX: was missing g*64
        #pragma unroll
        for (int dc = 0; dc < 2; ++dc) {
            const int off = (row * 128 + dc * 64 + hi * 16) ^ ((row & 7) << 4);
            f16x8 a = *(const f16x8*)(KP + off);
            #pragma unroll
            for (int qf = 0; qf < 4; ++qf)
                accs[kf][qf] = __builtin_amdgcn_mfma_f32_16x16x32_f16(a, qreg[qf][dc], accs[kf][qf], 0, 0, 0);
        }
    }

    // ---- bias + per-quarter max (lane keys: g*64 + kf*16 + hi*4 + r) ----
    float mq[4];
    #pragma unroll
    for (int qf = 0; qf < 4; ++qf) {
        const int q = qf * 16 + c15;
        float pa[4], pb[4];
        #pragma unroll
        for (int r = 0; r < 4; ++r)  pa[r] = posq[q][hi * 4 + r];
        #pragma unroll
        for (int kf = 0; kf < 4; ++kf) pb[kf] = posq[q][16 + g * 4 + kf];
        float mm = -1e30f;
        #pragma unroll
        for (int kf = 0; kf < 4; ++kf)
            #pragma unroll
            for (int r = 0; r < 4; ++r) {
                const float s = accs[kf][qf][r] + pa[r] + pb[kf];
                accs[kf][qf][r] = s;
                mm = fmaxf(mm, s);
            }
        mm = fmaxf(mm, __shfl_xor(mm, 16));
        mm = fmaxf(mm, __shfl_xor(mm, 32));
        mq[qf] = mm;
    }
    if (l < 16) {
        #pragma unroll
        for (int qf = 0; qf < 4; ++qf) red[g][qf * 16 + l] = mq[qf];
    }
    __syncthreads();   // B3: maxes visible; K reads done -> KP becomes P

    // ---- exp + sums + pack P into LDS [q][268 keys] fp16 ----
    float sums[4];
    #pragma unroll
    for (int qf = 0; qf < 4; ++qf) {
        const int q = qf * 16 + c15;
        const float mfull = fmaxf(fmaxf(red[0][q], red[1][q]), fmaxf(red[2][q], red[3][q]));
        float ss = 0.f;
        #pragma unroll
        for (int kf = 0; kf < 4; ++kf)
            #pragma unroll
            for (int r = 0; r < 4; ++r) {
                const float p = __expf(accs[kf][qf][r] - mfull);
                accs[kf][qf][r] = p;
                ss += p;
            }
        ss += __shfl_xor(ss, 16);
        ss += __shfl_xor(ss, 32);
        sums[qf] = ss;
        #pragma unroll
        for (int kf = 0; kf < 4; ++kf) {
            __half2 h01 = __floats2half2_rn(accs[kf][qf][0], accs[kf][qf][1]);
            __half2 h23 = __floats2half2_rn(accs[kf][qf][2], accs[kf][qf][3]);
            uint2 wv;
            wv.x = *(unsigned*)&h01;
            wv.y = *(unsigned*)&h23;
            *(uint2*)(KP + q * 536 + (g * 64 + kf * 16 + hi * 4) * 2) = wv;
        }
    }
    if (l < 16) {
        #pragma unroll
        for (int qf = 0; qf < 4; ++qf) red2[g][qf * 16 + l] = sums[qf];
    }
    __syncthreads();   // B4: P + sums visible

    // ---- PV via 16x16x16: wave g owns dims [g*16, g*16+16), all 256 keys ----
    f32x4 acco[4];
    #pragma unroll
    for (int qf = 0; qf < 4; ++qf) acco[qf] = (f32x4){0.f, 0.f, 0.f, 0.f};
    #pragma unroll
    for (int kc = 0; kc < 16; ++kc) {
        const f16x4 bf = *(const f16x4*)(VTl + (g * 16 + c15) * 536 + (kc * 16 + hi * 4) * 2);
        #pragma unroll
        for (int qf = 0; qf < 4; ++qf) {
            const f16x4 af = *(const f16x4*)(KP + (qf * 16 + c15) * 536 + (kc * 16 + hi * 4) * 2);
            acco[qf] = __builtin_amdgcn_mfma_f32_16x16x16f16(af, bf, acco[qf], 0, 0, 0);
        }
    }

    // ---- normalize + store (D: col=dim=c15, rows q=hi*4+r within frag) ----
    #pragma unroll
    for (int qf = 0; qf < 4; ++qf) {
        #pragma unroll
        for (int r = 0; r < 4; ++r) {
            const int q = qf * 16 + hi * 4 + r;
            const float den = red2[0][q] + red2[1][q] + red2[2][q] + red2[3][q];
            const float v = acco[qf][r] / den;
            const size_t pix = (size_t)((b * 64 + hb * 8 + (q >> 3)) * 64 + wb * 8 + (q & 7));
            obuf[pix * 512 + n * 64 + g * 16 + c15] = __float2half(v);
        }
    }
}

// ---------------------------------------------------------------------------
extern "C" void kernel_launch(void* const* d_in, const int* in_sizes, int n_in,
                              void* d_out, int out_size, void* d_ws, size_t ws_size,
                              hipStream_t stream)
{
    const float* x    = (const float*)d_in[0];
    const float* wq   = (const float*)d_in[1];
    const float* wkv  = (const float*)d_in[2];
    const float* wout = (const float*)d_in[3];
    const float* posw = (const float*)d_in[4];
    const float* posh = (const float*)d_in[5];
    float* out = (float*)d_out;

    // workspace: x16/vT share region A (x16 dead after proj; vT written after).
    const size_t NPIX = (size_t)M_TOT * 512;
    __half* x16 = (__half*)d_ws;            // 32 MB, becomes vT
    __half* vTb = x16;
    __half* wT  = x16 + NPIX;               // 1.5 MB
    __half* woT = wT + (size_t)1536 * 512;  // 0.5 MB
    __half* q16 = woT + (size_t)512 * 512;  // 32 MB
    __half* k16 = q16 + NPIX;               // 32 MB
    __half* v16 = k16 + NPIX;               // 32 MB
    __half* o16 = v16 + NPIX;               // 32 MB
    __half* zp  = o16 + NPIX;               // 256 B zero page

    hipMemsetAsync(zp, 0, 256, stream);

    conv_x<<<(M_TOT * 512) / (256 * 8), 256, 0, stream>>>(x, x16);
    conv_w<<<(2048 * 512) / 256, 256, 0, stream>>>(wq, wkv, wout, wT, woT);

    dim3 g1(M_TOT / 128, 12);
    mfma_gemm<0><<<g1, 256, 0, stream>>>(x16, wT, q16, k16, v16, nullptr);

    transpose_v<<<4096, 256, 0, stream>>>(v16, vTb);

    halo_attn<<<4096, 256, 0, stream>>>(q16, k16, vTb, posw, posh, zp, o16);

    dim3 g3(M_TOT / 128, 4);
    mfma_gemm<1><<<g3, 256, 0, stream>>>(o16, woT, nullptr, nullptr, nullptr, out);
}

// Round 6
// 243.263 us; speedup vs baseline: 6.6455x; 1.1016x over previous
//
#include <hip/hip_runtime.h>
#include <hip/hip_fp16.h>
#include <math.h>

typedef _Float16 f16x8 __attribute__((ext_vector_type(8)));
typedef _Float16 f16x4 __attribute__((ext_vector_type(4)));
typedef float    f32x4 __attribute__((ext_vector_type(4)));

#define M_TOT 32768   // 8*64*64 pixels

// ---------------------------------------------------------------------------
// async global->LDS, 16B per lane. LDS dest = wave-uniform base + lane*16.
// ---------------------------------------------------------------------------
__device__ __forceinline__ void gload16(const void* g, void* l) {
    __builtin_amdgcn_global_load_lds(
        (const __attribute__((address_space(1))) unsigned int*)g,
        (__attribute__((address_space(3))) unsigned int*)l, 16, 0, 0);
}

// ---------------------------------------------------------------------------
// x (fp32) -> fp16
// ---------------------------------------------------------------------------
__global__ __launch_bounds__(256) void conv_x(const float* __restrict__ x,
                                              __half* __restrict__ y) {
    const size_t i = ((size_t)blockIdx.x * 256 + threadIdx.x) * 8;
    float4 a = *(const float4*)&x[i];
    float4 b = *(const float4*)&x[i + 4];
    __half2 h[4];
    h[0] = __floats2half2_rn(a.x, a.y);
    h[1] = __floats2half2_rn(a.z, a.w);
    h[2] = __floats2half2_rn(b.x, b.y);
    h[3] = __floats2half2_rn(b.z, b.w);
    *(float4*)&y[i] = *(float4*)h;
}

// ---------------------------------------------------------------------------
// weights -> fp16, transposed to [n][k]; q-scale 0.125 folded into wq.
// ---------------------------------------------------------------------------
__global__ __launch_bounds__(256) void conv_w(const float* __restrict__ wq,
                                              const float* __restrict__ wkv,
                                              const float* __restrict__ wout,
                                              __half* __restrict__ wT,
                                              __half* __restrict__ woT) {
    const int id = blockIdx.x * 256 + threadIdx.x;   // < 2048*512
    const int nr = id >> 9, k = id & 511;
    if (nr < 512) {
        wT[(size_t)nr * 512 + k]  = __float2half(wq[k * 512 + nr] * 0.125f);
    } else if (nr < 1536) {
        wT[(size_t)nr * 512 + k]  = __float2half(wkv[k * 1024 + (nr - 512)]);
    } else {
        woT[(size_t)(nr - 1536) * 512 + k] = __float2half(wout[k * 512 + (nr - 1536)]);
    }
}

// ---------------------------------------------------------------------------
// fp16 MFMA GEMM (m97 structure), BM=BN=128, BK=32, 4 waves.
// MODE 0: proj epilogue (split q/k/v fp16). MODE 1: fp32 store to outf.
// ---------------------------------------------------------------------------
template <int MODE>
__global__ __launch_bounds__(256) void mfma_gemm(
    const __half* __restrict__ A, const __half* __restrict__ Bt,
    __half* __restrict__ q16, __half* __restrict__ k16, __half* __restrict__ v16,
    float* __restrict__ outf)
{
    __shared__ _Float16 As[128 * 32];
    __shared__ _Float16 Bs[128 * 32];

    const int t = threadIdx.x;
    const int l = t & 63, w = t >> 6;
    const int wr = w >> 1, wc = w & 1;
    const int bm = blockIdx.x, bn = blockIdx.y;

    f32x4 zero = {0.f, 0.f, 0.f, 0.f};
    f32x4 acc[4][4];
    #pragma unroll
    for (int i = 0; i < 4; ++i)
        #pragma unroll
        for (int j = 0; j < 4; ++j) acc[i][j] = zero;

    const int srow = w * 32 + (l >> 2);
    const int sch  = (l & 3) * 8;
    const size_t abase = (size_t)(bm * 128 + srow) * 512 + sch;
    const size_t bbase = (size_t)(bn * 128 + srow) * 512 + sch;
    _Float16* ldsA0 = &As[(w * 2 + 0) * 512];
    _Float16* ldsA1 = &As[(w * 2 + 1) * 512];
    _Float16* ldsB0 = &Bs[(w * 2 + 0) * 512];
    _Float16* ldsB1 = &Bs[(w * 2 + 1) * 512];

    const int lr = l & 15, lk = (l >> 4) * 8;

    for (int k0 = 0; k0 < 512; k0 += 32) {
        gload16(A  + abase + k0,            ldsA0);
        gload16(A  + abase + 16 * 512 + k0, ldsA1);
        gload16(Bt + bbase + k0,            ldsB0);
        gload16(Bt + bbase + 16 * 512 + k0, ldsB1);
        __syncthreads();

        f16x8 af[4], bf[4];
        #pragma unroll
        for (int i = 0; i < 4; ++i)
            af[i] = *(const f16x8*)&As[(wr * 64 + i * 16 + lr) * 32 + lk];
        #pragma unroll
        for (int j = 0; j < 4; ++j)
            bf[j] = *(const f16x8*)&Bs[(wc * 64 + j * 16 + lr) * 32 + lk];
        #pragma unroll
        for (int i = 0; i < 4; ++i)
            #pragma unroll
            for (int j = 0; j < 4; ++j)
                acc[i][j] = __builtin_amdgcn_mfma_f32_16x16x32_f16(af[i], bf[j], acc[i][j], 0, 0, 0);
        __syncthreads();
    }

    const int lq = l >> 4;
    #pragma unroll
    for (int i = 0; i < 4; ++i) {
        #pragma unroll
        for (int j = 0; j < 4; ++j) {
            #pragma unroll
            for (int r = 0; r < 4; ++r) {
                const int row = bm * 128 + wr * 64 + i * 16 + lq * 4 + r;
                const int col = bn * 128 + wc * 64 + j * 16 + lr;
                const float vv = acc[i][j][r];
                if (MODE == 1) {
                    outf[(size_t)row * 512 + col] = vv;
                } else {
                    if (col < 512) {
                        q16[(size_t)row * 512 + col] = __float2half(vv);
                    } else {
                        const int c2 = col - 512;
                        const int head = c2 >> 7, dd = c2 & 127;
                        __half* dst = (dd < 64) ? k16 : v16;
                        dst[(size_t)row * 512 + head * 64 + (dd & 63)] = __float2half(vv);
                    }
                }
            }
        }
    }
}

// ---------------------------------------------------------------------------
// V transpose: v16 [b*4096+px][n*64+d] -> vT [(b*8+n)*64+d][4096 px]
// ---------------------------------------------------------------------------
__global__ __launch_bounds__(256) void transpose_v(const __half* __restrict__ v16,
                                                   __half* __restrict__ vT) {
    __shared__ __half tile[64][72];
    const int wg = blockIdx.x;
    const int tl = wg & 63, n = (wg >> 6) & 7, b = wg >> 9;
    const int px0 = tl * 64;
    const int t = threadIdx.x;

    #pragma unroll
    for (int i = 0; i < 2; ++i) {
        const int c = i * 256 + t;           // 512 chunks of 8 halves
        const int px = c >> 3, dch = c & 7;
        float4 v = *(const float4*)(v16 + ((size_t)(b * 4096 + px0 + px)) * 512 + n * 64 + dch * 8);
        *(float4*)&tile[px][dch * 8] = v;
    }
    __syncthreads();
    const int d = t & 63, pc = t >> 6;       // 4 chunks of 16 px
    __half ov[16];
    #pragma unroll
    for (int j = 0; j < 16; ++j) ov[j] = tile[pc * 16 + j][d];
    __half* dst = vT + ((size_t)((b * 8 + n) * 64 + d)) * 4096 + px0 + pc * 16;
    *(float4*)&dst[0] = *(float4*)&ov[0];
    *(float4*)&dst[8] = *(float4*)&ov[8];
}

// ---------------------------------------------------------------------------
// MFMA halo attention. 4096 blocks x 4 waves; wave g owns key quarter
// [g*64, g*64+64) for QK^T/softmax and dim quarter [g*16,g*16+16) for PV.
// V consumed as B-frags loaded DIRECTLY from vT global (no LDS buffer).
// LDS 43.8 KB -> 3 blocks/CU. XCD-swizzled blockIdx (batch per XCD).
// ---------------------------------------------------------------------------
__global__ __launch_bounds__(256, 3) void halo_attn(
    const __half* __restrict__ qbuf, const __half* __restrict__ kbuf,
    const __half* __restrict__ vT,
    const float* __restrict__ posw, const float* __restrict__ posh,
    const __half* __restrict__ zp,
    __half* __restrict__ obuf)
{
    __shared__ __align__(16) char KP[64 * 520];   // 33280 B: postab -> K(swz) -> P
    __shared__ float posq[64][33];                // 8448 B
    __shared__ float red[4][64];
    __shared__ float red2[4][64];

    // XCD swizzle: contiguous 512-block chunk (one batch) per XCD
    const int hw = blockIdx.x;
    const int wg = (hw & 7) * 512 + (hw >> 3);
    const int wb = wg & 7, hb = (wg >> 3) & 7, n = (wg >> 6) & 7, b = wg >> 9;
    const int t = threadIdx.x;
    const int l = t & 63, g = t >> 6;
    const int hi = l >> 4, c15 = l & 15;

    // ---- V B-frags direct from vT: lane (c15,hi) -> dim g*16+c15,
    //      keys kc*16 + hi*4 + j (j=0..3 contiguous in x) ----
    f16x4 vfrag[16];
    {
        const __half* vrow = vT + ((size_t)((b * 8 + n) * 64 + g * 16 + c15)) * 4096;
        const int x0 = wb * 8 - 4 + hi * 4;
        const bool okx = (unsigned)x0 < 64u;
        #pragma unroll
        for (int kc = 0; kc < 16; ++kc) {
            const int y = hb * 8 - 4 + kc;
            const bool ok = okx && ((unsigned)y < 64u);
            const __half* p = ok ? (vrow + y * 64 + x0) : zp;
            vfrag[kc] = *(const f16x4*)p;
        }
    }

    // ---- stage pos tables transposed [idx][d] fp16 (overlay KP) ----
    __half* pwT = (__half*)KP;            // [31][72]
    __half* phT = pwT + 31 * 72;
    for (int j5 = t; j5 < 31 * 64; j5 += 256) {
        const int idx = j5 >> 6, d = j5 & 63;
        pwT[idx * 72 + d] = __float2half(posw[d * 31 + idx]);
        phT[idx * 72 + d] = __float2half(posh[d * 31 + idx]);
    }

    // ---- q row for posq (thread = q-row l, wave g computes c = g*8..+8) ----
    const int qrow = l;
    const int pixq = (b * 64 + hb * 8 + (qrow >> 3)) * 64 + wb * 8 + (qrow & 7);
    __half2 qh[32];
    {
        const __half* qsrc = qbuf + (size_t)pixq * 512 + n * 64;
        #pragma unroll
        for (int r = 0; r < 8; ++r) {
            float4 f = *(const float4*)&qsrc[r * 8];
            const __half2* qp = (const __half2*)&f;
            qh[r * 4 + 0] = qp[0]; qh[r * 4 + 1] = qp[1];
            qh[r * 4 + 2] = qp[2]; qh[r * 4 + 3] = qp[3];
        }
    }
    __syncthreads();   // B0: pos tables staged

    #pragma unroll
    for (int j = 0; j < 8; ++j) {
        const int c = g * 8 + j;
        const int idx = (c < 16) ? (c - (qrow & 7) + 15) : ((c - 16) - (qrow >> 3) + 15);
        const __half* tab = ((c < 16) ? pwT : phT) + idx * 72;
        __half2 a0 = __floats2half2_rn(0.f, 0.f), a1 = a0, a2 = a0, a3 = a0;
        #pragma unroll
        for (int d8 = 0; d8 < 8; ++d8) {
            float4 tv = *(const float4*)&tab[d8 * 8];
            const __half2* tp = (const __half2*)&tv;
            a0 = __hfma2(qh[d8 * 4 + 0], tp[0], a0);
            a1 = __hfma2(qh[d8 * 4 + 1], tp[1], a1);
            a2 = __hfma2(qh[d8 * 4 + 2], tp[2], a2);
            a3 = __hfma2(qh[d8 * 4 + 3], tp[3], a3);
        }
        const __half2 s2 = __hadd2(__hadd2(a0, a1), __hadd2(a2, a3));
        posq[qrow][c] = __low2float(s2) + __high2float(s2);
    }
    __syncthreads();   // B1: posq done, pos tables dead -> K region free

    // ---- stage K via global_load_lds, source pre-swizzled (^ (row&7)<<4) ----
    #pragma unroll
    for (int it = 0; it < 8; ++it) {
        const int cid = it * 256 + t;
        const int S = cid * 16;                       // linear LDS byte
        const int row = S >> 7;                       // key 0..255
        const int d0h = (((S & 127) >> 4) ^ (row & 7)) * 8;   // halves
        const int ky = hb * 8 - 4 + (row >> 4);
        const int kx = wb * 8 - 4 + (row & 15);
        const bool ok = ((unsigned)ky < 64u) && ((unsigned)kx < 64u);
        const __half* src = ok ? (kbuf + ((size_t)((b * 64 + ky) * 64 + kx)) * 512 + n * 64 + d0h)
                               : zp;
        gload16(src, KP + (it * 256 + g * 64) * 16);
    }

    // ---- Q fragments (B-operand of 16x16x32): qreg[qf][dc] ----
    f16x8 qreg[4][2];
    #pragma unroll
    for (int qf = 0; qf < 4; ++qf) {
        const int q = qf * 16 + c15;
        const size_t pix = (size_t)((b * 64 + hb * 8 + (q >> 3)) * 64 + wb * 8 + (q & 7));
        #pragma unroll
        for (int dc = 0; dc < 2; ++dc)
            qreg[qf][dc] = *(const f16x8*)(qbuf + pix * 512 + n * 64 + dc * 32 + hi * 8);
    }
    __syncthreads();   // B2: K staged

    // ---- QK^T: S^T frags, A=K (swizzled LDS, wave g's quarter), B=Q regs ----
    f32x4 accs[4][4];
    #pragma unroll
    for (int kf = 0; kf < 4; ++kf)
        #pragma unroll
        for (int qf = 0; qf < 4; ++qf) accs[kf][qf] = (f32x4){0.f, 0.f, 0.f, 0.f};

    #pragma unroll
    for (int kf = 0; kf < 4; ++kf) {
        const int row = g * 64 + kf * 16 + c15;
        #pragma unroll
        for (int dc = 0; dc < 2; ++dc) {
            const int off = (row * 128 + dc * 64 + hi * 16) ^ ((row & 7) << 4);
            f16x8 a = *(const f16x8*)(KP + off);
            #pragma unroll
            for (int qf = 0; qf < 4; ++qf)
                accs[kf][qf] = __builtin_amdgcn_mfma_f32_16x16x32_f16(a, qreg[qf][dc], accs[kf][qf], 0, 0, 0);
        }
    }

    // ---- bias + per-quarter max (lane keys: g*64 + kf*16 + hi*4 + r) ----
    float mq[4];
    #pragma unroll
    for (int qf = 0; qf < 4; ++qf) {
        const int q = qf * 16 + c15;
        float pa[4], pb[4];
        #pragma unroll
        for (int r = 0; r < 4; ++r)  pa[r] = posq[q][hi * 4 + r];
        #pragma unroll
        for (int kf = 0; kf < 4; ++kf) pb[kf] = posq[q][16 + g * 4 + kf];
        float mm = -1e30f;
        #pragma unroll
        for (int kf = 0; kf < 4; ++kf)
            #pragma unroll
            for (int r = 0; r < 4; ++r) {
                const float s = accs[kf][qf][r] + pa[r] + pb[kf];
                accs[kf][qf][r] = s;
                mm = fmaxf(mm, s);
            }
        mm = fmaxf(mm, __shfl_xor(mm, 16));
        mm = fmaxf(mm, __shfl_xor(mm, 32));
        mq[qf] = mm;
    }
    if (l < 16) {
        #pragma unroll
        for (int qf = 0; qf < 4; ++qf) red[g][qf * 16 + l] = mq[qf];
    }
    __syncthreads();   // B3: maxes visible; K reads done -> KP becomes P

    // ---- exp + sums + pack P into LDS [q] pitch 520B fp16 ----
    float sums[4];
    #pragma unroll
    for (int qf = 0; qf < 4; ++qf) {
        const int q = qf * 16 + c15;
        const float mfull = fmaxf(fmaxf(red[0][q], red[1][q]), fmaxf(red[2][q], red[3][q]));
        float ss = 0.f;
        #pragma unroll
        for (int kf = 0; kf < 4; ++kf)
            #pragma unroll
            for (int r = 0; r < 4; ++r) {
                const float p = __expf(accs[kf][qf][r] - mfull);
                accs[kf][qf][r] = p;
                ss += p;
            }
        ss += __shfl_xor(ss, 16);
        ss += __shfl_xor(ss, 32);
        sums[qf] = ss;
        #pragma unroll
        for (int kf = 0; kf < 4; ++kf) {
            __half2 h01 = __floats2half2_rn(accs[kf][qf][0], accs[kf][qf][1]);
            __half2 h23 = __floats2half2_rn(accs[kf][qf][2], accs[kf][qf][3]);
            uint2 wv;
            wv.x = *(unsigned*)&h01;
            wv.y = *(unsigned*)&h23;
            *(uint2*)(KP + q * 520 + (g * 64 + kf * 16 + hi * 4) * 2) = wv;
        }
    }
    if (l < 16) {
        #pragma unroll
        for (int qf = 0; qf < 4; ++qf) red2[g][qf * 16 + l] = sums[qf];
    }
    __syncthreads();   // B4: P + sums visible

    // ---- PV via 16x16x16: wave g owns dims [g*16, g*16+16), all 256 keys ----
    f32x4 acco[4];
    #pragma unroll
    for (int qf = 0; qf < 4; ++qf) acco[qf] = (f32x4){0.f, 0.f, 0.f, 0.f};
    #pragma unroll
    for (int kc = 0; kc < 16; ++kc) {
        const f16x4 bf = vfrag[kc];
        #pragma unroll
        for (int qf = 0; qf < 4; ++qf) {
            const f16x4 af = *(const f16x4*)(KP + (qf * 16 + c15) * 520 + (kc * 16 + hi * 4) * 2);
            acco[qf] = __builtin_amdgcn_mfma_f32_16x16x16f16(af, bf, acco[qf], 0, 0, 0);
        }
    }

    // ---- normalize + store (D: col=dim=c15, rows q=hi*4+r within frag) ----
    #pragma unroll
    for (int qf = 0; qf < 4; ++qf) {
        #pragma unroll
        for (int r = 0; r < 4; ++r) {
            const int q = qf * 16 + hi * 4 + r;
            const float den = red2[0][q] + red2[1][q] + red2[2][q] + red2[3][q];
            const float v = acco[qf][r] / den;
            const size_t pix = (size_t)((b * 64 + hb * 8 + (q >> 3)) * 64 + wb * 8 + (q & 7));
            obuf[pix * 512 + n * 64 + g * 16 + c15] = __float2half(v);
        }
    }
}

// ---------------------------------------------------------------------------
extern "C" void kernel_launch(void* const* d_in, const int* in_sizes, int n_in,
                              void* d_out, int out_size, void* d_ws, size_t ws_size,
                              hipStream_t stream)
{
    const float* x    = (const float*)d_in[0];
    const float* wq   = (const float*)d_in[1];
    const float* wkv  = (const float*)d_in[2];
    const float* wout = (const float*)d_in[3];
    const float* posw = (const float*)d_in[4];
    const float* posh = (const float*)d_in[5];
    float* out = (float*)d_out;

    // workspace: x16/vT share region A (x16 dead after proj; vT written after).
    const size_t NPIX = (size_t)M_TOT * 512;
    __half* x16 = (__half*)d_ws;            // 32 MB, becomes vT
    __half* vTb = x16;
    __half* wT  = x16 + NPIX;               // 1.5 MB
    __half* woT = wT + (size_t)1536 * 512;  // 0.5 MB
    __half* q16 = woT + (size_t)512 * 512;  // 32 MB
    __half* k16 = q16 + NPIX;               // 32 MB
    __half* v16 = k16 + NPIX;               // 32 MB
    __half* o16 = v16 + NPIX;               // 32 MB
    __half* zp  = o16 + NPIX;               // 256 B zero page

    hipMemsetAsync(zp, 0, 256, stream);

    conv_x<<<(M_TOT * 512) / (256 * 8), 256, 0, stream>>>(x, x16);
    conv_w<<<(2048 * 512) / 256, 256, 0, stream>>>(wq, wkv, wout, wT, woT);

    dim3 g1(M_TOT / 128, 12);
    mfma_gemm<0><<<g1, 256, 0, stream>>>(x16, wT, q16, k16, v16, nullptr);

    transpose_v<<<4096, 256, 0, stream>>>(v16, vTb);

    halo_attn<<<4096, 256, 0, stream>>>(q16, k16, vTb, posw, posh, zp, o16);

    dim3 g3(M_TOT / 128, 4);
    mfma_gemm<1><<<g3, 256, 0, stream>>>(o16, woT, nullptr, nullptr, nullptr, out);
}

// Round 7
// 227.194 us; speedup vs baseline: 7.1156x; 1.0707x over previous
//
#include <hip/hip_runtime.h>
#include <hip/hip_fp16.h>
#include <math.h>

typedef _Float16 f16x8 __attribute__((ext_vector_type(8)));
typedef _Float16 f16x4 __attribute__((ext_vector_type(4)));
typedef float    f32x4 __attribute__((ext_vector_type(4)));

#define M_TOT 32768   // 8*64*64 pixels

// ---------------------------------------------------------------------------
// async global->LDS, 16B per lane. LDS dest = wave-uniform base + lane*16.
// ---------------------------------------------------------------------------
__device__ __forceinline__ void gload16(const void* g, void* l) {
    __builtin_amdgcn_global_load_lds(
        (const __attribute__((address_space(1))) unsigned int*)g,
        (__attribute__((address_space(3))) unsigned int*)l, 16, 0, 0);
}

// ---------------------------------------------------------------------------
// x (fp32) -> fp16
// ---------------------------------------------------------------------------
__global__ __launch_bounds__(256) void conv_x(const float* __restrict__ x,
                                              __half* __restrict__ y) {
    const size_t i = ((size_t)blockIdx.x * 256 + threadIdx.x) * 8;
    float4 a = *(const float4*)&x[i];
    float4 b = *(const float4*)&x[i + 4];
    __half2 h[4];
    h[0] = __floats2half2_rn(a.x, a.y);
    h[1] = __floats2half2_rn(a.z, a.w);
    h[2] = __floats2half2_rn(b.x, b.y);
    h[3] = __floats2half2_rn(b.z, b.w);
    *(float4*)&y[i] = *(float4*)h;
}

// ---------------------------------------------------------------------------
// weights -> fp16, transposed to [n][k]; q-scale 0.125 folded into wq.
// ---------------------------------------------------------------------------
__global__ __launch_bounds__(256) void conv_w(const float* __restrict__ wq,
                                              const float* __restrict__ wkv,
                                              const float* __restrict__ wout,
                                              __half* __restrict__ wT,
                                              __half* __restrict__ woT) {
    const int id = blockIdx.x * 256 + threadIdx.x;   // < 2048*512
    const int nr = id >> 9, k = id & 511;
    if (nr < 512) {
        wT[(size_t)nr * 512 + k]  = __float2half(wq[k * 512 + nr] * 0.125f);
    } else if (nr < 1536) {
        wT[(size_t)nr * 512 + k]  = __float2half(wkv[k * 1024 + (nr - 512)]);
    } else {
        woT[(size_t)(nr - 1536) * 512 + k] = __float2half(wout[k * 512 + (nr - 1536)]);
    }
}

// ---------------------------------------------------------------------------
// fp16 MFMA GEMM (m97 structure), BM=BN=128, BK=32, 4 waves.
// MODE 0: proj epilogue -> q16, k16, and vT (value part pre-transposed).
// MODE 1: fp32 store to outf.
// ---------------------------------------------------------------------------
template <int MODE>
__global__ __launch_bounds__(256) void mfma_gemm(
    const __half* __restrict__ A, const __half* __restrict__ Bt,
    __half* __restrict__ q16, __half* __restrict__ k16, __half* __restrict__ vT,
    float* __restrict__ outf)
{
    __shared__ _Float16 As[128 * 32];
    __shared__ _Float16 Bs[128 * 32];

    const int t = threadIdx.x;
    const int l = t & 63, w = t >> 6;
    const int wr = w >> 1, wc = w & 1;
    const int bm = blockIdx.x, bn = blockIdx.y;

    f32x4 zero = {0.f, 0.f, 0.f, 0.f};
    f32x4 acc[4][4];
    #pragma unroll
    for (int i = 0; i < 4; ++i)
        #pragma unroll
        for (int j = 0; j < 4; ++j) acc[i][j] = zero;

    const int srow = w * 32 + (l >> 2);
    const int sch  = (l & 3) * 8;
    const size_t abase = (size_t)(bm * 128 + srow) * 512 + sch;
    const size_t bbase = (size_t)(bn * 128 + srow) * 512 + sch;
    _Float16* ldsA0 = &As[(w * 2 + 0) * 512];
    _Float16* ldsA1 = &As[(w * 2 + 1) * 512];
    _Float16* ldsB0 = &Bs[(w * 2 + 0) * 512];
    _Float16* ldsB1 = &Bs[(w * 2 + 1) * 512];

    const int lr = l & 15, lk = (l >> 4) * 8;

    for (int k0 = 0; k0 < 512; k0 += 32) {
        gload16(A  + abase + k0,            ldsA0);
        gload16(A  + abase + 16 * 512 + k0, ldsA1);
        gload16(Bt + bbase + k0,            ldsB0);
        gload16(Bt + bbase + 16 * 512 + k0, ldsB1);
        __syncthreads();

        f16x8 af[4], bf[4];
        #pragma unroll
        for (int i = 0; i < 4; ++i)
            af[i] = *(const f16x8*)&As[(wr * 64 + i * 16 + lr) * 32 + lk];
        #pragma unroll
        for (int j = 0; j < 4; ++j)
            bf[j] = *(const f16x8*)&Bs[(wc * 64 + j * 16 + lr) * 32 + lk];
        #pragma unroll
        for (int i = 0; i < 4; ++i)
            #pragma unroll
            for (int j = 0; j < 4; ++j)
                acc[i][j] = __builtin_amdgcn_mfma_f32_16x16x32_f16(af[i], bf[j], acc[i][j], 0, 0, 0);
        __syncthreads();
    }

    const int lq = l >> 4;
    #pragma unroll
    for (int i = 0; i < 4; ++i) {
        #pragma unroll
        for (int j = 0; j < 4; ++j) {
            const int row0 = bm * 128 + wr * 64 + i * 16 + lq * 4;
            const int col  = bn * 128 + wc * 64 + j * 16 + lr;
            if (MODE == 1) {
                #pragma unroll
                for (int r = 0; r < 4; ++r)
                    outf[(size_t)(row0 + r) * 512 + col] = acc[i][j][r];
            } else if (bn < 4) {
                #pragma unroll
                for (int r = 0; r < 4; ++r)
                    q16[(size_t)(row0 + r) * 512 + col] = __float2half(acc[i][j][r]);
            } else if (wc == 0) {           // key part
                const int head = bn - 4, d2 = j * 16 + lr;
                #pragma unroll
                for (int r = 0; r < 4; ++r)
                    k16[(size_t)(row0 + r) * 512 + head * 64 + d2] = __float2half(acc[i][j][r]);
            } else {                        // value part -> vT[(b*8+head)*64+d][pix]
                const int head = bn - 4, d2 = j * 16 + lr;
                const int bb = row0 >> 12, pix = row0 & 4095;  // 4 consecutive pixels
                f16x4 pv;
                #pragma unroll
                for (int r = 0; r < 4; ++r) pv[r] = (_Float16)acc[i][j][r];
                *(f16x4*)(vT + ((size_t)((bb * 8 + head) * 64 + d2)) * 4096 + pix) = pv;
            }
        }
    }
}

// ---------------------------------------------------------------------------
// MFMA halo attention. 4096 blocks x 4 waves; wave g owns key quarter
// [g*64, g*64+64) for QK^T/softmax and dim quarter [g*16,g*16+16) for PV.
// Pos bias via MFMA: RWT[idx][q] = pos_w^T . Q^T (reuses qreg B-frags).
// V B-frags loaded directly from vT global. LDS 52.7 KB -> 3 blocks/CU.
// ---------------------------------------------------------------------------
__global__ __launch_bounds__(256, 3) void halo_attn(
    const __half* __restrict__ qbuf, const __half* __restrict__ kbuf,
    const __half* __restrict__ vT,
    const float* __restrict__ posw, const float* __restrict__ posh,
    const __half* __restrict__ zp,
    __half* __restrict__ obuf)
{
    __shared__ __align__(16) char KP[64 * 520];   // 33280 B: posA-tiles -> K(swz) -> P
    __shared__ float RWT[32][68];                 // rel_w^T [idx][q] f32
    __shared__ float RHT[32][68];                 // rel_h^T [idx][q] f32
    __shared__ float red[4][64];
    __shared__ float red2[4][64];

    // XCD swizzle: contiguous 512-block chunk (one batch) per XCD
    const int hw = blockIdx.x;
    const int wg = (hw & 7) * 512 + (hw >> 3);
    const int wb = wg & 7, hb = (wg >> 3) & 7, n = (wg >> 6) & 7, b = wg >> 9;
    const int t = threadIdx.x;
    const int l = t & 63, g = t >> 6;
    const int hi = l >> 4, c15 = l & 15;

    // ---- V B-frags direct from vT: lane (c15,hi) -> dim g*16+c15,
    //      keys kc*16 + hi*4 + j (contiguous in x) ----
    f16x4 vfrag[16];
    {
        const __half* vrow = vT + ((size_t)((b * 8 + n) * 64 + g * 16 + c15)) * 4096;
        const int x0 = wb * 8 - 4 + hi * 4;
        const bool okx = (unsigned)x0 < 64u;
        #pragma unroll
        for (int kc = 0; kc < 16; ++kc) {
            const int y = hb * 8 - 4 + kc;
            const bool ok = okx && ((unsigned)y < 64u);
            const __half* p = ok ? (vrow + y * 64 + x0) : zp;
            vfrag[kc] = *(const f16x4*)p;
        }
    }

    // ---- stage pos tables as swizzled MFMA A-tiles: KP + tb*4096,
    //      entry (idx,d) at byte (idx*128 + d*2) ^ ((idx&7)<<4); row 31 = 0 ----
    for (int j5 = t; j5 < 4096; j5 += 256) {
        const int tb = j5 >> 11, idx = (j5 >> 6) & 31, d = j5 & 63;
        const float* src = tb ? posh : posw;
        const float v = (idx < 31) ? src[d * 31 + idx] : 0.f;
        *(__half*)(KP + tb * 4096 + ((idx * 128 + d * 2) ^ ((idx & 7) << 4))) = __float2half(v);
    }

    // ---- Q fragments (B-operand of 16x16x32): qreg[qf][dc] ----
    f16x8 qreg[4][2];
    #pragma unroll
    for (int qf = 0; qf < 4; ++qf) {
        const int q = qf * 16 + c15;
        const size_t pix = (size_t)((b * 64 + hb * 8 + (q >> 3)) * 64 + wb * 8 + (q & 7));
        #pragma unroll
        for (int dc = 0; dc < 2; ++dc)
            qreg[qf][dc] = *(const f16x8*)(qbuf + pix * 512 + n * 64 + dc * 32 + hi * 8);
    }
    __syncthreads();   // B0: pos A-tiles staged

    // ---- pos MFMA: wave g -> table tb=g>>1, idx-half ih=g&1 (8 MFMA) ----
    f32x4 accp[4];
    #pragma unroll
    for (int qf = 0; qf < 4; ++qf) accp[qf] = (f32x4){0.f, 0.f, 0.f, 0.f};
    {
        const int tb = g >> 1, ih = g & 1;
        const char* base = KP + tb * 4096;
        const int row = ih * 16 + c15;
        #pragma unroll
        for (int dc = 0; dc < 2; ++dc) {
            const int off = (row * 128 + dc * 64 + hi * 16) ^ ((row & 7) << 4);
            f16x8 a = *(const f16x8*)(base + off);
            #pragma unroll
            for (int qf = 0; qf < 4; ++qf)
                accp[qf] = __builtin_amdgcn_mfma_f32_16x16x32_f16(a, qreg[qf][dc], accp[qf], 0, 0, 0);
        }
    }
    __syncthreads();   // B1: pos-table reads done -> KP free for K

    // ---- issue K staging via global_load_lds (source pre-swizzled) ----
    #pragma unroll
    for (int it = 0; it < 8; ++it) {
        const int cid = it * 256 + t;
        const int S = cid * 16;                       // linear LDS byte
        const int row = S >> 7;                       // key 0..255
        const int d0h = (((S & 127) >> 4) ^ (row & 7)) * 8;   // halves
        const int ky = hb * 8 - 4 + (row >> 4);
        const int kx = wb * 8 - 4 + (row & 15);
        const bool ok = ((unsigned)ky < 64u) && ((unsigned)kx < 64u);
        const __half* src = ok ? (kbuf + ((size_t)((b * 64 + ky) * 64 + kx)) * 512 + n * 64 + d0h)
                               : zp;
        gload16(src, KP + (it * 256 + g * 64) * 16);
    }

    // ---- write pos D-frags to RWT/RHT f32 (overlaps with K loads in flight) ----
    {
        const int tb = g >> 1, ih = g & 1;
        float (*dst)[68] = tb ? RHT : RWT;
        #pragma unroll
        for (int qf = 0; qf < 4; ++qf)
            #pragma unroll
            for (int r = 0; r < 4; ++r)
                dst[ih * 16 + hi * 4 + r][qf * 16 + c15] = accp[qf][r];
    }
    __syncthreads();   // B2: K landed, RWT/RHT visible

    // ---- QK^T: S^T frags, A=K (swizzled LDS, wave g's quarter), B=Q regs ----
    f32x4 accs[4][4];
    #pragma unroll
    for (int kf = 0; kf < 4; ++kf)
        #pragma unroll
        for (int qf = 0; qf < 4; ++qf) accs[kf][qf] = (f32x4){0.f, 0.f, 0.f, 0.f};

    #pragma unroll
    for (int kf = 0; kf < 4; ++kf) {
        const int row = g * 64 + kf * 16 + c15;
        #pragma unroll
        for (int dc = 0; dc < 2; ++dc) {
            const int off = (row * 128 + dc * 64 + hi * 16) ^ ((row & 7) << 4);
            f16x8 a = *(const f16x8*)(KP + off);
            #pragma unroll
            for (int qf = 0; qf < 4; ++qf)
                accs[kf][qf] = __builtin_amdgcn_mfma_f32_16x16x32_f16(a, qreg[qf][dc], accs[kf][qf], 0, 0, 0);
        }
    }

    // ---- bias + per-quarter max (lane keys: g*64 + kf*16 + hi*4 + r) ----
    float mq[4];
    #pragma unroll
    for (int qf = 0; qf < 4; ++qf) {
        const int q = qf * 16 + c15;
        const int qj = q & 7, qi = q >> 3;
        float pa[4], pb[4];
        #pragma unroll
        for (int r = 0; r < 4; ++r)  pa[r] = RWT[hi * 4 + r - qj + 15][q];
        #pragma unroll
        for (int kf = 0; kf < 4; ++kf) pb[kf] = RHT[g * 4 + kf - qi + 15][q];
        float mm = -1e30f;
        #pragma unroll
        for (int kf = 0; kf < 4; ++kf)
            #pragma unroll
            for (int r = 0; r < 4; ++r) {
                const float s = accs[kf][qf][r] + pa[r] + pb[kf];
                accs[kf][qf][r] = s;
                mm = fmaxf(mm, s);
            }
        mm = fmaxf(mm, __shfl_xor(mm, 16));
        mm = fmaxf(mm, __shfl_xor(mm, 32));
        mq[qf] = mm;
    }
    if (l < 16) {
        #pragma unroll
        for (int qf = 0; qf < 4; ++qf) red[g][qf * 16 + l] = mq[qf];
    }
    __syncthreads();   // B3: maxes visible; K reads done -> KP becomes P

    // ---- exp + sums + pack P into LDS [q] pitch 520B fp16 ----
    float sums[4];
    #pragma unroll
    for (int qf = 0; qf < 4; ++qf) {
        const int q = qf * 16 + c15;
        const float mfull = fmaxf(fmaxf(red[0][q], red[1][q]), fmaxf(red[2][q], red[3][q]));
        float ss = 0.f;
        #pragma unroll
        for (int kf = 0; kf < 4; ++kf)
            #pragma unroll
            for (int r = 0; r < 4; ++r) {
                const float p = __expf(accs[kf][qf][r] - mfull);
                accs[kf][qf][r] = p;
                ss += p;
            }
        ss += __shfl_xor(ss, 16);
        ss += __shfl_xor(ss, 32);
        sums[qf] = ss;
        #pragma unroll
        for (int kf = 0; kf < 4; ++kf) {
            __half2 h01 = __floats2half2_rn(accs[kf][qf][0], accs[kf][qf][1]);
            __half2 h23 = __floats2half2_rn(accs[kf][qf][2], accs[kf][qf][3]);
            uint2 wv;
            wv.x = *(unsigned*)&h01;
            wv.y = *(unsigned*)&h23;
            *(uint2*)(KP + q * 520 + (g * 64 + kf * 16 + hi * 4) * 2) = wv;
        }
    }
    if (l < 16) {
        #pragma unroll
        for (int qf = 0; qf < 4; ++qf) red2[g][qf * 16 + l] = sums[qf];
    }
    __syncthreads();   // B4: P + sums visible

    // ---- PV via 16x16x16: wave g owns dims [g*16, g*16+16), all 256 keys ----
    f32x4 acco[4];
    #pragma unroll
    for (int qf = 0; qf < 4; ++qf) acco[qf] = (f32x4){0.f, 0.f, 0.f, 0.f};
    #pragma unroll
    for (int kc = 0; kc < 16; ++kc) {
        const f16x4 bf = vfrag[kc];
        #pragma unroll
        for (int qf = 0; qf < 4; ++qf) {
            const f16x4 af = *(const f16x4*)(KP + (qf * 16 + c15) * 520 + (kc * 16 + hi * 4) * 2);
            acco[qf] = __builtin_amdgcn_mfma_f32_16x16x16f16(af, bf, acco[qf], 0, 0, 0);
        }
    }

    // ---- normalize + store (D: col=dim=c15, rows q=hi*4+r within frag) ----
    #pragma unroll
    for (int qf = 0; qf < 4; ++qf) {
        #pragma unroll
        for (int r = 0; r < 4; ++r) {
            const int q = qf * 16 + hi * 4 + r;
            const float den = red2[0][q] + red2[1][q] + red2[2][q] + red2[3][q];
            const float v = acco[qf][r] / den;
            const size_t pix = (size_t)((b * 64 + hb * 8 + (q >> 3)) * 64 + wb * 8 + (q & 7));
            obuf[pix * 512 + n * 64 + g * 16 + c15] = __float2half(v);
        }
    }
}

// ---------------------------------------------------------------------------
extern "C" void kernel_launch(void* const* d_in, const int* in_sizes, int n_in,
                              void* d_out, int out_size, void* d_ws, size_t ws_size,
                              hipStream_t stream)
{
    const float* x    = (const float*)d_in[0];
    const float* wq   = (const float*)d_in[1];
    const float* wkv  = (const float*)d_in[2];
    const float* wout = (const float*)d_in[3];
    const float* posw = (const float*)d_in[4];
    const float* posh = (const float*)d_in[5];
    float* out = (float*)d_out;

    // fp16 workspace (162 MB): vT now written directly by proj epilogue.
    const size_t NPIX = (size_t)M_TOT * 512;
    __half* x16 = (__half*)d_ws;            // 32 MB
    __half* wT  = x16 + NPIX;               // 1.5 MB
    __half* woT = wT + (size_t)1536 * 512;  // 0.5 MB
    __half* q16 = woT + (size_t)512 * 512;  // 32 MB
    __half* k16 = q16 + NPIX;               // 32 MB
    __half* vT  = k16 + NPIX;               // 32 MB  [(b*8+n)*64+d][4096 px]
    __half* o16 = vT + NPIX;                // 32 MB
    __half* zp  = o16 + NPIX;               // 256 B zero page

    hipMemsetAsync(zp, 0, 256, stream);

    conv_x<<<(M_TOT * 512) / (256 * 8), 256, 0, stream>>>(x, x16);
    conv_w<<<(2048 * 512) / 256, 256, 0, stream>>>(wq, wkv, wout, wT, woT);

    dim3 g1(M_TOT / 128, 12);
    mfma_gemm<0><<<g1, 256, 0, stream>>>(x16, wT, q16, k16, vT, nullptr);

    halo_attn<<<4096, 256, 0, stream>>>(q16, k16, vT, posw, posh, zp, o16);

    dim3 g3(M_TOT / 128, 4);
    mfma_gemm<1><<<g3, 256, 0, stream>>>(o16, woT, nullptr, nullptr, nullptr, out);
}